// Round 5
// baseline (295.985 us; speedup 1.0000x reference)
//
#include <hip/hip_runtime.h>
#include <hip/hip_bf16.h>
#include <stdint.h>

#define N_NODES 50000
#define N_EDGES 800000
#define HDIM 64
#define SCAN_N (N_NODES + 1)

// ---- workspace layout (CSR path) ----
#define MSUM_OFF   0                                  // 50000*64*4 = 12.8 MB f32
#define EP_OFF     12800000                           // 800000*16 B packed edges
#define DEG_OFF    (EP_OFF + 12800000)
#define OFFS_OFF   (DEG_OFF + 204800)
#define POS_OFF    (OFFS_OFF + 204800)
#define FB_OFF     (POS_OFF + 204800)
#define W1T_OFF    (FB_OFF + (size_t)N_NODES * HDIM * 2)
#define W2T_OFF    (W1T_OFF + 16384)
#define U1T_OFF    (W2T_OFF + 8192)
#define U2T_OFF    (U1T_OFF + 8192)
#define CST_OFF    (U2T_OFF + 8192)
#define WS_NEED    (CST_OFF + 4096)

// fused prep kernel block ranges
#define CVT_BLOCKS   1563             // ceil(3.2M/8/256) feat->bf16
#define PREPW_BLOCKS 82               // transposed weights + consts
#define MZ_BLOCKS    3125             // msum zero: 12.8MB / (256*16B)
#define HIST_BLOCKS  1024             // dst histogram

typedef __attribute__((ext_vector_type(8))) short short8;
typedef __attribute__((ext_vector_type(4))) float floatx4;

__device__ __forceinline__ float bf2f(unsigned short u) {
    union { unsigned int i; float f; } v; v.i = ((unsigned int)u) << 16; return v.f;
}
__device__ __forceinline__ unsigned short f2bf(float f) {
    __hip_bfloat16 h = __float2bfloat16(f);
    return *reinterpret_cast<unsigned short*>(&h);
}

__device__ __forceinline__ int detect_is_bf16(const unsigned short* p) {
    int cnt = 0;
    #pragma unroll
    for (int i = 0; i < 64; ++i) {
        unsigned short b = p[i];
        int e = (b >> 7) & 0xFF;
        cnt += ((e >= 97 && e <= 157) || (b & 0x7FFF) == 0) ? 1 : 0;
    }
    return cnt >= 56;
}

__device__ __forceinline__ float getf(const void* p, unsigned int i, int isb) {
    return isb ? bf2f(((const unsigned short*)p)[i]) : ((const float*)p)[i];
}

__device__ __forceinline__ short8 get8bf(const void* p, unsigned int i, int isb) {
    if (isb) {
        return *reinterpret_cast<const short8*>((const short*)p + i);
    } else {
        const float4 f0 = *reinterpret_cast<const float4*>((const float*)p + i);
        const float4 f1 = *reinterpret_cast<const float4*>((const float*)p + i + 4);
        short8 a;
        a[0] = (short)f2bf(f0.x); a[1] = (short)f2bf(f0.y);
        a[2] = (short)f2bf(f0.z); a[3] = (short)f2bf(f0.w);
        a[4] = (short)f2bf(f1.x); a[5] = (short)f2bf(f1.y);
        a[6] = (short)f2bf(f1.z); a[7] = (short)f2bf(f1.w);
        return a;
    }
}

#define COMPILER_FENCE() asm volatile("" ::: "memory")
#define WAIT_LDS() __builtin_amdgcn_s_waitcnt(0xC07F)   // lgkmcnt(0) only

// ---------------------------------------------------------------------------
// Fused prep: feat->bf16 | transposed weights + f32 consts | msum zero | hist
// ---------------------------------------------------------------------------
__global__ __launch_bounds__(256) void prep_kernel(
    const void* __restrict__ feat, unsigned short* __restrict__ fb,
    const void* __restrict__ W1, const void* __restrict__ W2,
    const void* __restrict__ U1, const void* __restrict__ U2,
    const void* __restrict__ b1, const void* __restrict__ b2,
    const void* __restrict__ we, const void* __restrict__ be,
    unsigned short* __restrict__ w1t, unsigned short* __restrict__ w2t,
    unsigned short* __restrict__ u1t, unsigned short* __restrict__ u2t,
    float* __restrict__ cst,
    const int* __restrict__ dst, int* __restrict__ deg,
    uint4* __restrict__ msumz)
{
    const int b = blockIdx.x;
    if (b < CVT_BLOCKS) {
        const int isb = detect_is_bf16((const unsigned short*)feat);
        int i = (b * 256 + threadIdx.x) * 8;
        if (i >= N_NODES * HDIM) return;
        if (isb) {
            *reinterpret_cast<uint4*>(fb + i) =
                *reinterpret_cast<const uint4*>((const unsigned short*)feat + i);
        } else {
            float4 f0 = *reinterpret_cast<const float4*>((const float*)feat + i);
            float4 f1 = *reinterpret_cast<const float4*>((const float*)feat + i + 4);
            ushort4 a = {f2bf(f0.x), f2bf(f0.y), f2bf(f0.z), f2bf(f0.w)};
            ushort4 c = {f2bf(f1.x), f2bf(f1.y), f2bf(f1.z), f2bf(f1.w)};
            *reinterpret_cast<ushort4*>(fb + i)     = a;
            *reinterpret_cast<ushort4*>(fb + i + 4) = c;
        }
    } else if (b < CVT_BLOCKS + PREPW_BLOCKS) {
        const int isb = detect_is_bf16((const unsigned short*)feat);
        int idx = (b - CVT_BLOCKS) * 256 + threadIdx.x;
        if (idx < 8192) {                               // W1T [64][128]
            int n = idx >> 7, k = idx & 127;
            w1t[idx] = f2bf(getf(W1, k * 64 + n, isb));
        } else if (idx < 12288) {                       // W2T [64][64]
            int i = idx - 8192, n = i >> 6, k = i & 63;
            w2t[i] = f2bf(getf(W2, k * 64 + n, isb));
        } else if (idx < 16384) {                       // U1T
            int i = idx - 12288, n = i >> 6, k = i & 63;
            u1t[i] = f2bf(getf(U1, k * 64 + n, isb));
        } else if (idx < 20480) {                       // U2T
            int i = idx - 16384, n = i >> 6, k = i & 63;
            u2t[i] = f2bf(getf(U2, k * 64 + n, isb));
        } else if (idx < 20737) {                       // f32 consts table
            int i = idx - 20480;
            float v;
            if (i < 64)       v = getf(b1, i, isb);
            else if (i < 128) v = getf(W1, 128 * 64 + (i - 64), isb);   // sqd row
            else if (i < 192) v = getf(b2, i - 128, isb);
            else if (i < 256) v = getf(we, i - 192, isb);
            else              v = getf(be, 0, isb);
            cst[i] = v;
        }
    } else if (b < CVT_BLOCKS + PREPW_BLOCKS + MZ_BLOCKS) {
        int i = (b - CVT_BLOCKS - PREPW_BLOCKS) * 256 + threadIdx.x;
        if (i < N_NODES * HDIM / 4)
            msumz[i] = (uint4){0u, 0u, 0u, 0u};
    } else {
        int e0 = (b - CVT_BLOCKS - PREPW_BLOCKS - MZ_BLOCKS) * 256 + threadIdx.x;
        for (int e = e0; e < N_EDGES; e += HIST_BLOCKS * 256)
            atomicAdd(&deg[dst[e]], 1);
    }
}

// ---------------------------------------------------------------------------
// Single-launch scan: 1 block x 1024 threads, 49 coalesced segments,
// shfl-based wave scan (3 barriers per segment). Replaces scan1/2/3.
// ---------------------------------------------------------------------------
__global__ __launch_bounds__(1024) void scan_onepass_kernel(
    const int* __restrict__ deg, int* __restrict__ offs, int* __restrict__ pos)
{
    __shared__ int wsum[16];
    const int tid  = threadIdx.x;
    const int wid  = tid >> 6;
    const int lane = tid & 63;
    int run = 0;
    for (int seg = 0; seg < 49; ++seg) {
        int g = seg * 1024 + tid;
        int v = (g < SCAN_N) ? deg[g] : 0;
        int x = v;
        #pragma unroll
        for (int off = 1; off < 64; off <<= 1) {
            int t = __shfl_up(x, off);
            if (lane >= off) x += t;
        }
        if (lane == 63) wsum[wid] = x;
        __syncthreads();
        if (wid == 0) {
            int w = (lane < 16) ? wsum[lane] : 0;
            #pragma unroll
            for (int off = 1; off < 16; off <<= 1) {
                int t = __shfl_up(w, off);
                if (lane >= off) w += t;
            }
            if (lane < 16) wsum[lane] = w;
        }
        __syncthreads();
        int wexcl = (wid == 0) ? 0 : wsum[wid - 1];
        int tot   = wsum[15];
        int excl  = run + wexcl + (x - v);
        if (g < SCAN_N) { offs[g] = excl; pos[g] = excl; }
        run += tot;
        __syncthreads();
    }
}

// ---------------------------------------------------------------------------
// Permute: counting-sort edges by dst; pack {src, dst, sqd} per slot.
// ---------------------------------------------------------------------------
__global__ __launch_bounds__(256) void permute_kernel(
    const void* __restrict__ feat, const void* __restrict__ xpos,
    const int* __restrict__ src, const int* __restrict__ dst,
    int* __restrict__ pos, uint4* __restrict__ epack)
{
    const int isb = detect_is_bf16((const unsigned short*)feat);
    int e = blockIdx.x * 256 + threadIdx.x;
    if (e < N_EDGES) {
        int s = src[e], d = dst[e];
        int slot = atomicAdd(&pos[d], 1);
        float dx = getf(xpos, s * 3 + 0, isb) - getf(xpos, d * 3 + 0, isb);
        float dy = getf(xpos, s * 3 + 1, isb) - getf(xpos, d * 3 + 1, isb);
        float dz = getf(xpos, s * 3 + 2, isb) - getf(xpos, d * 3 + 2, isb);
        float sqd = dx * dx + dy * dy + dz * dz;
        uint4 p;
        p.x = (unsigned int)s;
        p.y = (unsigned int)d;
        p.z = __float_as_uint(sqd);
        p.w = 0u;
        epack[slot] = p;
    }
}

// ---------------------------------------------------------------------------
// Edge kernel, 512 threads. CSR path: DUAL-TILE ILP — each wave processes
// two independent 16-edge tiles per iteration (two memory/MFMA chains in
// flight; shared sW1/sW2 fragment reads). In-register segmented reduce ->
// one coalesced 64-lane f32 atomic per dst segment.
// ---------------------------------------------------------------------------
template <bool CSR>
__global__ __launch_bounds__(512, 4) void edge_kernel(
    const unsigned short* __restrict__ fbf,
    const unsigned short* __restrict__ w1t, const unsigned short* __restrict__ w2t,
    const float* __restrict__ cst,
    const void* __restrict__ feat, const void* __restrict__ xpos,
    const int* __restrict__ src, const int* __restrict__ dst,
    const uint4* __restrict__ epack,
    const void* __restrict__ W1, const void* __restrict__ b1,
    const void* __restrict__ W2, const void* __restrict__ b2,
    const void* __restrict__ we, const void* __restrict__ be,
    float* __restrict__ msum, unsigned int msum_cap)
{
    __shared__ __align__(16) short sW1[16][64][8];   // frag f=c*4+nt, lane, 16B
    __shared__ __align__(16) short sW2[8][64][8];
    __shared__ __align__(16) short sA2[2][8][16][72];

    const int tid  = threadIdx.x;
    const int wave = tid >> 6;
    const int lane = tid & 63;
    const int l15  = lane & 15;
    const int quad = lane >> 4;
    const int rowb = quad * 4;

    float b1r[4], w1lr[4], b2r[4], wer[4];
    float ber;
    short8 bw1[4][4];    // fallback-only
    short8 bw2[2][4];

    if constexpr (CSR) {
        // stage transposed weights into fragment-major LDS (once per block)
        for (int i = tid; i < 16 * 64; i += 512) {
            int f = i >> 6, l = i & 63;
            int n = (f & 3) * 16 + (l & 15);
            int k0 = (f >> 2) * 32 + (l >> 4) * 8;
            *reinterpret_cast<short8*>(&sW1[f][l][0]) =
                *reinterpret_cast<const short8*>(w1t + n * 128 + k0);
        }
        for (int i = tid; i < 8 * 64; i += 512) {
            int f = i >> 6, l = i & 63;
            int n = (f & 3) * 16 + (l & 15);
            int k0 = (f >> 2) * 32 + (l >> 4) * 8;
            *reinterpret_cast<short8*>(&sW2[f][l][0]) =
                *reinterpret_cast<const short8*>(w2t + n * 64 + k0);
        }
        #pragma unroll
        for (int nt = 0; nt < 4; ++nt) {
            int n = nt * 16 + l15;
            b1r[nt]  = cst[n];
            w1lr[nt] = cst[64 + n];
            b2r[nt]  = cst[128 + n];
            wer[nt]  = cst[192 + n];
        }
        ber = cst[256];
        __syncthreads();

        const int nbiter = N_EDGES / 256;    // 3125 (256 edges per block-iter)
        for (int it = blockIdx.x; it < nbiter; it += gridDim.x) {
            const int ebase = it * 256 + wave * 16;

            int sidx = 0, didx = 0;
            float sqd = 0.f;
            if (lane < 32) {
                int e = ebase + l15 + ((lane >> 4) << 7);   // lanes 16-31: +128
                uint4 p = epack[e];
                sidx = (int)p.x;
                didx = (int)p.y;
                sqd  = __uint_as_float(p.z);
            }
            const int snA = __shfl(sidx, l15);
            const int dnA = __shfl(didx, l15);
            const int snB = __shfl(sidx, l15 + 16);
            const int dnB = __shfl(didx, l15 + 16);

            // ---- gathers for both tiles (8 independent loads in flight) ----
            short8 caA[4], caB[4];
            #pragma unroll
            for (int c = 0; c < 4; ++c) {
                const int nA = (c < 2) ? snA : dnA;
                const int nB = (c < 2) ? snB : dnB;
                caA[c] = *reinterpret_cast<const short8*>(
                    (const short*)fbf + (unsigned int)nA * 64u + (c & 1) * 32 + quad * 8);
                caB[c] = *reinterpret_cast<const short8*>(
                    (const short*)fbf + (unsigned int)nB * 64u + (c & 1) * 32 + quad * 8);
            }

            // ---- layer 1 (both tiles, shared B frags) ----
            floatx4 accA[4], accB[4];
            #pragma unroll
            for (int nt = 0; nt < 4; ++nt) {
                accA[nt] = (floatx4){0.f, 0.f, 0.f, 0.f};
                accB[nt] = (floatx4){0.f, 0.f, 0.f, 0.f};
            }
            #pragma unroll
            for (int c = 0; c < 4; ++c) {
                #pragma unroll
                for (int nt = 0; nt < 4; ++nt) {
                    short8 wb = *reinterpret_cast<const short8*>(&sW1[c * 4 + nt][lane][0]);
                    accA[nt] = __builtin_amdgcn_mfma_f32_16x16x32_bf16(caA[c], wb, accA[nt], 0, 0, 0);
                    accB[nt] = __builtin_amdgcn_mfma_f32_16x16x32_bf16(caB[c], wb, accB[nt], 0, 0, 0);
                }
            }

            // ---- epilogue 1 -> LDS (both tiles) ----
            float sqA[4], sqB[4];
            #pragma unroll
            for (int r = 0; r < 4; ++r) {
                sqA[r] = __shfl(sqd, rowb + r);
                sqB[r] = __shfl(sqd, 16 + rowb + r);
            }
            #pragma unroll
            for (int nt = 0; nt < 4; ++nt)
                #pragma unroll
                for (int r = 0; r < 4; ++r) {
                    float vA = fmaxf(accA[nt][r] + b1r[nt] + sqA[r] * w1lr[nt], 0.f);
                    float vB = fmaxf(accB[nt][r] + b1r[nt] + sqB[r] * w1lr[nt], 0.f);
                    sA2[0][wave][rowb + r][nt * 16 + l15] = (short)f2bf(vA);
                    sA2[1][wave][rowb + r][nt * 16 + l15] = (short)f2bf(vB);
                }
            COMPILER_FENCE();
            WAIT_LDS();

            // ---- layer 2 (both tiles, shared B frags) ----
            floatx4 acc2A[4], acc2B[4];
            #pragma unroll
            for (int nt = 0; nt < 4; ++nt) {
                acc2A[nt] = (floatx4){0.f, 0.f, 0.f, 0.f};
                acc2B[nt] = (floatx4){0.f, 0.f, 0.f, 0.f};
            }
            #pragma unroll
            for (int c = 0; c < 2; ++c) {
                short8 aA = *reinterpret_cast<const short8*>(&sA2[0][wave][l15][c * 32 + quad * 8]);
                short8 aB = *reinterpret_cast<const short8*>(&sA2[1][wave][l15][c * 32 + quad * 8]);
                #pragma unroll
                for (int nt = 0; nt < 4; ++nt) {
                    short8 wb = *reinterpret_cast<const short8*>(&sW2[c * 4 + nt][lane][0]);
                    acc2A[nt] = __builtin_amdgcn_mfma_f32_16x16x32_bf16(aA, wb, acc2A[nt], 0, 0, 0);
                    acc2B[nt] = __builtin_amdgcn_mfma_f32_16x16x32_bf16(aB, wb, acc2B[nt], 0, 0, 0);
                }
            }
            COMPILER_FENCE();

            // ---- epilogue 2: relu, gate (both tiles) ----
            float mvA[4][4], mvB[4][4];
            float pA[4] = {0.f, 0.f, 0.f, 0.f};
            float pB[4] = {0.f, 0.f, 0.f, 0.f};
            #pragma unroll
            for (int nt = 0; nt < 4; ++nt)
                #pragma unroll
                for (int r = 0; r < 4; ++r) {
                    float vA = fmaxf(acc2A[nt][r] + b2r[nt], 0.f);
                    float vB = fmaxf(acc2B[nt][r] + b2r[nt], 0.f);
                    mvA[nt][r] = vA;
                    mvB[nt][r] = vB;
                    pA[r] += vA * wer[nt];
                    pB[r] += vB * wer[nt];
                }
            #pragma unroll
            for (int off = 1; off < 16; off <<= 1)
                #pragma unroll
                for (int r = 0; r < 4; ++r) {
                    pA[r] += __shfl_xor(pA[r], off);
                    pB[r] += __shfl_xor(pB[r], off);
                }
            float gA[4], gB[4];
            #pragma unroll
            for (int r = 0; r < 4; ++r) {
                gA[r] = 1.f / (1.f + __expf(-(pA[r] + ber)));
                gB[r] = 1.f / (1.f + __expf(-(pB[r] + ber)));
            }

            // ---- in-register segmented reduce (both tiles) ----
            int grp = (lane >> 4) & 1;
            int nd = __shfl(didx, grp * 16 + ((l15 + 1) & 15));
            int flag = (lane < 32) && ((l15 == 15) || (nd != didx));
            unsigned long long bal = __ballot(flag);
            unsigned int mA = (unsigned int)(bal & 0xFFFFull);
            unsigned int mB = (unsigned int)((bal >> 16) & 0xFFFFull);

            int lo = 0;
            while (mA) {
                int hi = __ffs(mA) - 1;
                float s0 = 0.f, s1 = 0.f, s2 = 0.f, s3 = 0.f;
                #pragma unroll
                for (int r = 0; r < 4; ++r) {
                    int gr = rowb + r;
                    float g = (gr >= lo && gr <= hi) ? gA[r] : 0.f;
                    s0 += g * mvA[0][r];
                    s1 += g * mvA[1][r];
                    s2 += g * mvA[2][r];
                    s3 += g * mvA[3][r];
                }
                s0 += __shfl_xor(s0, 16); s0 += __shfl_xor(s0, 32);
                s1 += __shfl_xor(s1, 16); s1 += __shfl_xor(s1, 32);
                s2 += __shfl_xor(s2, 16); s2 += __shfl_xor(s2, 32);
                s3 += __shfl_xor(s3, 16); s3 += __shfl_xor(s3, 32);
                int d = __shfl(didx, hi);
                float v = (quad == 0) ? s0 : (quad == 1) ? s1 : (quad == 2) ? s2 : s3;
                unsafeAtomicAdd(&msum[(unsigned int)d * 64u + (unsigned int)quad * 16u + l15], v);
                lo = hi + 1;
                mA &= mA - 1;
            }
            lo = 0;
            while (mB) {
                int hi = __ffs(mB) - 1;
                float s0 = 0.f, s1 = 0.f, s2 = 0.f, s3 = 0.f;
                #pragma unroll
                for (int r = 0; r < 4; ++r) {
                    int gr = rowb + r;
                    float g = (gr >= lo && gr <= hi) ? gB[r] : 0.f;
                    s0 += g * mvB[0][r];
                    s1 += g * mvB[1][r];
                    s2 += g * mvB[2][r];
                    s3 += g * mvB[3][r];
                }
                s0 += __shfl_xor(s0, 16); s0 += __shfl_xor(s0, 32);
                s1 += __shfl_xor(s1, 16); s1 += __shfl_xor(s1, 32);
                s2 += __shfl_xor(s2, 16); s2 += __shfl_xor(s2, 32);
                s3 += __shfl_xor(s3, 16); s3 += __shfl_xor(s3, 32);
                int d = __shfl(didx, 16 + hi);
                float v = (quad == 0) ? s0 : (quad == 1) ? s1 : (quad == 2) ? s2 : s3;
                unsafeAtomicAdd(&msum[(unsigned int)d * 64u + (unsigned int)quad * 16u + l15], v);
                lo = hi + 1;
                mB &= mB - 1;
            }
        }
    } else {
        // ---------------- fallback path (no workspace): r4-proven ----------------
        const int isb = detect_is_bf16((const unsigned short*)feat);
        #pragma unroll
        for (int c = 0; c < 4; ++c)
            #pragma unroll
            for (int nt = 0; nt < 4; ++nt) {
                short8 b;
                #pragma unroll
                for (int j = 0; j < 8; ++j)
                    b[j] = (short)f2bf(getf(W1, (c * 32 + quad * 8 + j) * 64 + nt * 16 + l15, isb));
                bw1[c][nt] = b;
            }
        #pragma unroll
        for (int c = 0; c < 2; ++c)
            #pragma unroll
            for (int nt = 0; nt < 4; ++nt) {
                short8 b;
                #pragma unroll
                for (int j = 0; j < 8; ++j)
                    b[j] = (short)f2bf(getf(W2, (c * 32 + quad * 8 + j) * 64 + nt * 16 + l15, isb));
                bw2[c][nt] = b;
            }
        #pragma unroll
        for (int nt = 0; nt < 4; ++nt) {
            int n = nt * 16 + l15;
            b1r[nt]  = getf(b1, n, isb);
            w1lr[nt] = getf(W1, 128 * 64 + n, isb);
            b2r[nt]  = getf(b2, n, isb);
            wer[nt]  = getf(we, n, isb);
        }
        ber = getf(be, 0, isb);

        const int ntiles = N_EDGES / 128;
        for (int t = blockIdx.x; t < ntiles; t += gridDim.x) {
            const int ebase = t * 128 + wave * 16;
            int sidx = 0, didx = 0;
            float sqd = 0.f;
            if (lane < 16) {
                int e = ebase + lane;
                sidx = src[e];
                didx = dst[e];
                float dx = getf(xpos, sidx * 3 + 0, isb) - getf(xpos, didx * 3 + 0, isb);
                float dy = getf(xpos, sidx * 3 + 1, isb) - getf(xpos, didx * 3 + 1, isb);
                float dz = getf(xpos, sidx * 3 + 2, isb) - getf(xpos, didx * 3 + 2, isb);
                sqd = dx * dx + dy * dy + dz * dz;
            }
            const int sn     = __shfl(sidx, l15);
            const int dn_row = __shfl(didx, l15);

            floatx4 acc[4];
            #pragma unroll
            for (int nt = 0; nt < 4; ++nt) acc[nt] = (floatx4){0.f, 0.f, 0.f, 0.f};
            #pragma unroll
            for (int c = 0; c < 4; ++c) {
                const int node = (c < 2) ? sn : dn_row;
                const unsigned int aoff = (unsigned int)node * 64u + (c & 1) * 32 + quad * 8;
                short8 a = get8bf(feat, aoff, isb);
                #pragma unroll
                for (int nt = 0; nt < 4; ++nt)
                    acc[nt] = __builtin_amdgcn_mfma_f32_16x16x32_bf16(a, bw1[c][nt], acc[nt], 0, 0, 0);
            }

            float sq[4];
            #pragma unroll
            for (int r = 0; r < 4; ++r) sq[r] = __shfl(sqd, rowb + r);
            #pragma unroll
            for (int nt = 0; nt < 4; ++nt)
                #pragma unroll
                for (int r = 0; r < 4; ++r) {
                    float v = fmaxf(acc[nt][r] + b1r[nt] + sq[r] * w1lr[nt], 0.f);
                    sA2[0][wave][rowb + r][nt * 16 + l15] = (short)f2bf(v);
                }
            COMPILER_FENCE();
            WAIT_LDS();

            floatx4 acc2[4];
            #pragma unroll
            for (int nt = 0; nt < 4; ++nt) acc2[nt] = (floatx4){0.f, 0.f, 0.f, 0.f};
            #pragma unroll
            for (int c = 0; c < 2; ++c) {
                short8 a = *reinterpret_cast<const short8*>(&sA2[0][wave][l15][c * 32 + quad * 8]);
                #pragma unroll
                for (int nt = 0; nt < 4; ++nt)
                    acc2[nt] = __builtin_amdgcn_mfma_f32_16x16x32_bf16(a, bw2[c][nt], acc2[nt], 0, 0, 0);
            }
            COMPILER_FENCE();

            float mval[4][4];
            float part[4] = {0.f, 0.f, 0.f, 0.f};
            #pragma unroll
            for (int nt = 0; nt < 4; ++nt)
                #pragma unroll
                for (int r = 0; r < 4; ++r) {
                    float v = fmaxf(acc2[nt][r] + b2r[nt], 0.f);
                    mval[nt][r] = v;
                    part[r] += v * wer[nt];
                }
            #pragma unroll
            for (int off = 1; off < 16; off <<= 1)
                #pragma unroll
                for (int r = 0; r < 4; ++r) part[r] += __shfl_xor(part[r], off);
            float gate[4];
            #pragma unroll
            for (int r = 0; r < 4; ++r)
                gate[r] = 1.f / (1.f + __expf(-(part[r] + ber)));

            #pragma unroll
            for (int r = 0; r < 4; ++r) {
                int dn = __shfl(didx, rowb + r);
                unsigned int base = (unsigned int)dn * 64u;
                if (base + 64u <= msum_cap) {
                    #pragma unroll
                    for (int nt = 0; nt < 4; ++nt)
                        unsafeAtomicAdd(&msum[base + nt * 16 + l15], mval[nt][r] * gate[r]);
                }
            }
        }
    }
}

// ---------------------------------------------------------------------------
// Node kernel: per wave a 16-node MFMA M-tile; reads f32 msum directly.
// ---------------------------------------------------------------------------
__global__ __launch_bounds__(256, 2) void node_kernel(
    const float* __restrict__ msum,
    const unsigned short* __restrict__ u1t, const unsigned short* __restrict__ u2t,
    const void* __restrict__ feat,
    const void* __restrict__ U1, const void* __restrict__ c1v,
    const void* __restrict__ U2, const void* __restrict__ c2v,
    void* __restrict__ out)
{
    __shared__ __align__(16) short sT[4][16][72];
    __shared__ __align__(16) float sF[4][16][68];

    const int isb  = detect_is_bf16((const unsigned short*)feat);
    const int tid  = threadIdx.x;
    const int wave = tid >> 6;
    const int lane = tid & 63;
    const int l15  = lane & 15;
    const int quad = lane >> 4;

    short8 u1f[2][4], u2f[2][4];
    if (u1t) {
        #pragma unroll
        for (int nt = 0; nt < 4; ++nt) {
            const int n = nt * 16 + l15;
            #pragma unroll
            for (int c = 0; c < 2; ++c) {
                u1f[c][nt] = *reinterpret_cast<const short8*>(u1t + n * 64 + c * 32 + quad * 8);
                u2f[c][nt] = *reinterpret_cast<const short8*>(u2t + n * 64 + c * 32 + quad * 8);
            }
        }
    } else {
        #pragma unroll
        for (int c = 0; c < 2; ++c)
            #pragma unroll
            for (int nt = 0; nt < 4; ++nt) {
                short8 a, b;
                #pragma unroll
                for (int j = 0; j < 8; ++j) {
                    int k = c * 32 + quad * 8 + j, n = nt * 16 + l15;
                    a[j] = (short)f2bf(getf(U1, k * 64 + n, isb));
                    b[j] = (short)f2bf(getf(U2, k * 64 + n, isb));
                }
                u1f[c][nt] = a; u2f[c][nt] = b;
            }
    }
    float c1r[4], c2r[4];
    #pragma unroll
    for (int nt = 0; nt < 4; ++nt) {
        c1r[nt] = getf(c1v, nt * 16 + l15, isb);
        c2r[nt] = getf(c2v, nt * 16 + l15, isb);
    }
    const int rowb = quad * 4;

    const int ntile = (N_NODES + 15) / 16;   // 3125
    const int t = blockIdx.x * 4 + wave;
    if (t < ntile) {
        const int node = t * 16 + l15;

        // ---- message sum (f32 msum) + h fragments ----
        short8 ah[2];
        #pragma unroll
        for (int c = 0; c < 2; ++c) {
            unsigned int off = (unsigned int)node * 64u + c * 32 + quad * 8;
            float4 m0 = *reinterpret_cast<const float4*>(msum + off);
            float4 m1 = *reinterpret_cast<const float4*>(msum + off + 4);
            float mv[8] = {m0.x, m0.y, m0.z, m0.w, m1.x, m1.y, m1.z, m1.w};
            float hv[8];
            if (isb) {
                short8 fv = *reinterpret_cast<const short8*>((const short*)feat + off);
                #pragma unroll
                for (int j = 0; j < 8; ++j) hv[j] = bf2f((unsigned short)fv[j]);
            } else {
                float4 f0 = *reinterpret_cast<const float4*>((const float*)feat + off);
                float4 f1 = *reinterpret_cast<const float4*>((const float*)feat + off + 4);
                hv[0] = f0.x; hv[1] = f0.y; hv[2] = f0.z; hv[3] = f0.w;
                hv[4] = f1.x; hv[5] = f1.y; hv[6] = f1.z; hv[7] = f1.w;
            }
            short8 a;
            #pragma unroll
            for (int j = 0; j < 8; ++j) a[j] = (short)f2bf(mv[j] + hv[j]);
            ah[c] = a;
        }

        // ---- layer 1: relu(h@U1+c1) ----
        floatx4 acc[4];
        #pragma unroll
        for (int nt = 0; nt < 4; ++nt) acc[nt] = (floatx4){0.f, 0.f, 0.f, 0.f};
        #pragma unroll
        for (int c = 0; c < 2; ++c)
            #pragma unroll
            for (int nt = 0; nt < 4; ++nt)
                acc[nt] = __builtin_amdgcn_mfma_f32_16x16x32_bf16(ah[c], u1f[c][nt], acc[nt], 0, 0, 0);

        #pragma unroll
        for (int nt = 0; nt < 4; ++nt)
            #pragma unroll
            for (int r = 0; r < 4; ++r) {
                float v = fmaxf(acc[nt][r] + c1r[nt], 0.f);
                sT[wave][rowb + r][nt * 16 + l15] = (short)f2bf(v);
            }
        COMPILER_FENCE();
        WAIT_LDS();

        // ---- layer 2 ----
        floatx4 acc2[4];
        #pragma unroll
        for (int nt = 0; nt < 4; ++nt) acc2[nt] = (floatx4){0.f, 0.f, 0.f, 0.f};
        #pragma unroll
        for (int c = 0; c < 2; ++c) {
            short8 a = *reinterpret_cast<const short8*>(&sT[wave][l15][c * 32 + quad * 8]);
            #pragma unroll
            for (int nt = 0; nt < 4; ++nt)
                acc2[nt] = __builtin_amdgcn_mfma_f32_16x16x32_bf16(a, u2f[c][nt], acc2[nt], 0, 0, 0);
        }
        COMPILER_FENCE();

        // ---- epilogue: D-layout -> f32 LDS -> row-coalesced (+feat) store ----
        #pragma unroll
        for (int nt = 0; nt < 4; ++nt)
            #pragma unroll
            for (int r = 0; r < 4; ++r)
                sF[wave][rowb + r][nt * 16 + l15] = acc2[nt][r] + c2r[nt];
        COMPILER_FENCE();
        WAIT_LDS();

        const unsigned int ob = (unsigned int)node * 64u + quad * 16;
        if (isb) {
            const unsigned short* fp = (const unsigned short*)feat + ob;
            unsigned short* op = (unsigned short*)out + ob;
            #pragma unroll
            for (int k = 0; k < 2; ++k) {
                ushort4 o0, o1;
                float4 v0 = *reinterpret_cast<const float4*>(&sF[wave][l15][quad * 16 + k * 8]);
                float4 v1 = *reinterpret_cast<const float4*>(&sF[wave][l15][quad * 16 + k * 8 + 4]);
                const ushort4 f0 = *reinterpret_cast<const ushort4*>(fp + k * 8);
                const ushort4 f1 = *reinterpret_cast<const ushort4*>(fp + k * 8 + 4);
                o0.x = f2bf(v0.x + bf2f(f0.x)); o0.y = f2bf(v0.y + bf2f(f0.y));
                o0.z = f2bf(v0.z + bf2f(f0.z)); o0.w = f2bf(v0.w + bf2f(f0.w));
                o1.x = f2bf(v1.x + bf2f(f1.x)); o1.y = f2bf(v1.y + bf2f(f1.y));
                o1.z = f2bf(v1.z + bf2f(f1.z)); o1.w = f2bf(v1.w + bf2f(f1.w));
                *reinterpret_cast<ushort4*>(op + k * 8)     = o0;
                *reinterpret_cast<ushort4*>(op + k * 8 + 4) = o1;
            }
        } else {
            const float* fp = (const float*)feat + ob;
            float* op = (float*)out + ob;
            #pragma unroll
            for (int k = 0; k < 4; ++k) {
                float4 v = *reinterpret_cast<const float4*>(&sF[wave][l15][quad * 16 + k * 4]);
                float4 f = *reinterpret_cast<const float4*>(fp + k * 4);
                float4 o = {v.x + f.x, v.y + f.y, v.z + f.z, v.w + f.w};
                *reinterpret_cast<float4*>(op + k * 4) = o;
            }
        }
        COMPILER_FENCE();
    }
}

extern "C" void kernel_launch(void* const* d_in, const int* in_sizes, int n_in,
                              void* d_out, int out_size, void* d_ws, size_t ws_size,
                              hipStream_t stream) {
    const void* feat = d_in[0];
    const void* x    = d_in[1];
    const int* src   = (const int*)d_in[2];
    const int* dst   = (const int*)d_in[3];
    const void* W1   = d_in[4];
    const void* b1   = d_in[5];
    const void* W2   = d_in[6];
    const void* b2   = d_in[7];
    const void* we   = d_in[8];
    const void* be   = d_in[9];
    const void* U1   = d_in[10];
    const void* c1   = d_in[11];
    const void* U2   = d_in[12];
    const void* c2   = d_in[13];
    char* ws = (char*)d_ws;

    if (ws_size >= WS_NEED) {
        float* msum = (float*)(ws + MSUM_OFF);
        uint4* epack = (uint4*)(ws + EP_OFF);
        int* deg  = (int*)(ws + DEG_OFF);
        int* offs = (int*)(ws + OFFS_OFF);
        int* pos  = (int*)(ws + POS_OFF);
        unsigned short* fb  = (unsigned short*)(ws + FB_OFF);
        unsigned short* w1t = (unsigned short*)(ws + W1T_OFF);
        unsigned short* w2t = (unsigned short*)(ws + W2T_OFF);
        unsigned short* u1t = (unsigned short*)(ws + U1T_OFF);
        unsigned short* u2t = (unsigned short*)(ws + U2T_OFF);
        float* cst = (float*)(ws + CST_OFF);

        hipMemsetAsync(deg, 0, 204800, stream);
        prep_kernel<<<CVT_BLOCKS + PREPW_BLOCKS + MZ_BLOCKS + HIST_BLOCKS, 256, 0, stream>>>(
            feat, fb, W1, W2, U1, U2, b1, b2, we, be,
            w1t, w2t, u1t, u2t, cst, dst, deg, (uint4*)msum);
        scan_onepass_kernel<<<1, 1024, 0, stream>>>(deg, offs, pos);
        permute_kernel<<<(N_EDGES + 255) / 256, 256, 0, stream>>>(feat, x, src, dst, pos, epack);
        edge_kernel<true><<<625, 512, 0, stream>>>(fb, w1t, w2t, cst, feat, x, src, dst, epack,
                                                   W1, b1, W2, b2, we, be,
                                                   msum, (unsigned int)(N_NODES * HDIM));
        node_kernel<<<((N_NODES + 15) / 16 + 3) / 4, 256, 0, stream>>>(
            msum, u1t, u2t, feat, U1, c1, U2, c2, d_out);
    } else {
        float* msum = (float*)ws;
        size_t need = (size_t)N_NODES * HDIM * sizeof(float);
        size_t clr  = need < ws_size ? need : ws_size;
        unsigned int cap = (unsigned int)(ws_size / sizeof(float));
        if (cap > (unsigned int)(N_NODES * HDIM)) cap = (unsigned int)(N_NODES * HDIM);

        hipMemsetAsync(msum, 0, clr, stream);
        edge_kernel<false><<<1250, 512, 0, stream>>>(nullptr, nullptr, nullptr, nullptr,
                                                     feat, x, src, dst,
                                                     nullptr, W1, b1, W2, b2, we, be,
                                                     msum, cap);
        node_kernel<<<((N_NODES + 15) / 16 + 3) / 4, 256, 0, stream>>>(
            msum, nullptr, nullptr, feat, U1, c1, U2, c2, d_out);
    }
}

// Round 6
// 276.374 us; speedup vs baseline: 1.0710x; 1.0710x over previous
//
#include <hip/hip_runtime.h>
#include <hip/hip_bf16.h>
#include <stdint.h>

#define N_NODES 50000
#define N_EDGES 800000
#define HDIM 64
#define SCAN_N (N_NODES + 1)

// ---- workspace layout (CSR path) ----
#define MSUM_OFF   0                                  // 50000*64*4 = 12.8 MB f32
#define EP_OFF     12800000                           // 800000*16 B packed edges
#define DEG_OFF    (EP_OFF + 12800000)
#define OFFS_OFF   (DEG_OFF + 204800)
#define POS_OFF    (OFFS_OFF + 204800)
#define FB_OFF     (POS_OFF + 204800)
#define W1T_OFF    (FB_OFF + (size_t)N_NODES * HDIM * 2)
#define W2T_OFF    (W1T_OFF + 16384)
#define U1T_OFF    (W2T_OFF + 8192)
#define U2T_OFF    (U1T_OFF + 8192)
#define CST_OFF    (U2T_OFF + 8192)
#define WS_NEED    (CST_OFF + 4096)

// fused prep kernel block ranges
#define CVT_BLOCKS   1563             // ceil(3.2M/8/256) feat->bf16
#define PREPW_BLOCKS 82               // transposed weights + consts
#define MZ_BLOCKS    3125             // msum zero: 12.8MB / (256*16B)
#define HIST_BLOCKS  1024             // dst histogram

typedef __attribute__((ext_vector_type(8))) short short8;
typedef __attribute__((ext_vector_type(4))) float floatx4;

__device__ __forceinline__ float bf2f(unsigned short u) {
    union { unsigned int i; float f; } v; v.i = ((unsigned int)u) << 16; return v.f;
}
// software RNE (cold paths / host-safe)
__device__ __forceinline__ unsigned short f2bf(float f) {
    __hip_bfloat16 h = __float2bfloat16(f);
    return *reinterpret_cast<unsigned short*>(&h);
}
// hardware RNE convert: 1 VALU op (hot epilogues)
__device__ __forceinline__ unsigned short f2bf_fast(float f) {
    unsigned int r;
    asm("v_cvt_pk_bf16_f32 %0, %1, %1" : "=v"(r) : "v"(f));
    return (unsigned short)r;
}

__device__ __forceinline__ int detect_is_bf16(const unsigned short* p) {
    int cnt = 0;
    #pragma unroll
    for (int i = 0; i < 64; ++i) {
        unsigned short b = p[i];
        int e = (b >> 7) & 0xFF;
        cnt += ((e >= 97 && e <= 157) || (b & 0x7FFF) == 0) ? 1 : 0;
    }
    return cnt >= 56;
}

__device__ __forceinline__ float getf(const void* p, unsigned int i, int isb) {
    return isb ? bf2f(((const unsigned short*)p)[i]) : ((const float*)p)[i];
}

__device__ __forceinline__ short8 get8bf(const void* p, unsigned int i, int isb) {
    if (isb) {
        return *reinterpret_cast<const short8*>((const short*)p + i);
    } else {
        const float4 f0 = *reinterpret_cast<const float4*>((const float*)p + i);
        const float4 f1 = *reinterpret_cast<const float4*>((const float*)p + i + 4);
        short8 a;
        a[0] = (short)f2bf(f0.x); a[1] = (short)f2bf(f0.y);
        a[2] = (short)f2bf(f0.z); a[3] = (short)f2bf(f0.w);
        a[4] = (short)f2bf(f1.x); a[5] = (short)f2bf(f1.y);
        a[6] = (short)f2bf(f1.z); a[7] = (short)f2bf(f1.w);
        return a;
    }
}

#define COMPILER_FENCE() asm volatile("" ::: "memory")
#define WAIT_LDS() __builtin_amdgcn_s_waitcnt(0xC07F)   // lgkmcnt(0) only

// ---------------------------------------------------------------------------
// Fused prep: feat->bf16 | transposed weights + f32 consts | msum zero | hist
// ---------------------------------------------------------------------------
__global__ __launch_bounds__(256) void prep_kernel(
    const void* __restrict__ feat, unsigned short* __restrict__ fb,
    const void* __restrict__ W1, const void* __restrict__ W2,
    const void* __restrict__ U1, const void* __restrict__ U2,
    const void* __restrict__ b1, const void* __restrict__ b2,
    const void* __restrict__ we, const void* __restrict__ be,
    unsigned short* __restrict__ w1t, unsigned short* __restrict__ w2t,
    unsigned short* __restrict__ u1t, unsigned short* __restrict__ u2t,
    float* __restrict__ cst,
    const int* __restrict__ dst, int* __restrict__ deg,
    uint4* __restrict__ msumz)
{
    const int b = blockIdx.x;
    if (b < CVT_BLOCKS) {
        const int isb = detect_is_bf16((const unsigned short*)feat);
        int i = (b * 256 + threadIdx.x) * 8;
        if (i >= N_NODES * HDIM) return;
        if (isb) {
            *reinterpret_cast<uint4*>(fb + i) =
                *reinterpret_cast<const uint4*>((const unsigned short*)feat + i);
        } else {
            float4 f0 = *reinterpret_cast<const float4*>((const float*)feat + i);
            float4 f1 = *reinterpret_cast<const float4*>((const float*)feat + i + 4);
            ushort4 a = {f2bf(f0.x), f2bf(f0.y), f2bf(f0.z), f2bf(f0.w)};
            ushort4 c = {f2bf(f1.x), f2bf(f1.y), f2bf(f1.z), f2bf(f1.w)};
            *reinterpret_cast<ushort4*>(fb + i)     = a;
            *reinterpret_cast<ushort4*>(fb + i + 4) = c;
        }
    } else if (b < CVT_BLOCKS + PREPW_BLOCKS) {
        const int isb = detect_is_bf16((const unsigned short*)feat);
        int idx = (b - CVT_BLOCKS) * 256 + threadIdx.x;
        if (idx < 8192) {                               // W1T [64][128]
            int n = idx >> 7, k = idx & 127;
            w1t[idx] = f2bf(getf(W1, k * 64 + n, isb));
        } else if (idx < 12288) {                       // W2T [64][64]
            int i = idx - 8192, n = i >> 6, k = i & 63;
            w2t[i] = f2bf(getf(W2, k * 64 + n, isb));
        } else if (idx < 16384) {                       // U1T
            int i = idx - 12288, n = i >> 6, k = i & 63;
            u1t[i] = f2bf(getf(U1, k * 64 + n, isb));
        } else if (idx < 20480) {                       // U2T
            int i = idx - 16384, n = i >> 6, k = i & 63;
            u2t[i] = f2bf(getf(U2, k * 64 + n, isb));
        } else if (idx < 20737) {                       // f32 consts table
            int i = idx - 20480;
            float v;
            if (i < 64)       v = getf(b1, i, isb);
            else if (i < 128) v = getf(W1, 128 * 64 + (i - 64), isb);   // sqd row
            else if (i < 192) v = getf(b2, i - 128, isb);
            else if (i < 256) v = getf(we, i - 192, isb);
            else              v = getf(be, 0, isb);
            cst[i] = v;
        }
    } else if (b < CVT_BLOCKS + PREPW_BLOCKS + MZ_BLOCKS) {
        int i = (b - CVT_BLOCKS - PREPW_BLOCKS) * 256 + threadIdx.x;
        if (i < N_NODES * HDIM / 4)
            msumz[i] = (uint4){0u, 0u, 0u, 0u};
    } else {
        int e0 = (b - CVT_BLOCKS - PREPW_BLOCKS - MZ_BLOCKS) * 256 + threadIdx.x;
        for (int e = e0; e < N_EDGES; e += HIST_BLOCKS * 256)
            atomicAdd(&deg[dst[e]], 1);
    }
}

// ---------------------------------------------------------------------------
// CSR scan (multi-block, proven — fused variants regressed twice)
// ---------------------------------------------------------------------------
__global__ void scan1_kernel(const int* __restrict__ deg, int* __restrict__ part) {
    __shared__ int s[1024];
    int g = blockIdx.x * 1024 + threadIdx.x;
    s[threadIdx.x] = (g < SCAN_N) ? deg[g] : 0;
    __syncthreads();
    for (int off = 512; off > 0; off >>= 1) {
        if (threadIdx.x < off) s[threadIdx.x] += s[threadIdx.x + off];
        __syncthreads();
    }
    if (threadIdx.x == 0) part[blockIdx.x] = s[0];
}

__global__ void scan2_kernel(int* __restrict__ part, int nparts) {
    if (threadIdx.x == 0) {
        int run = 0;
        for (int i = 0; i < nparts; ++i) { int t = part[i]; part[i] = run; run += t; }
    }
}

__global__ void scan3_kernel(const int* __restrict__ deg, const int* __restrict__ part,
                             int* __restrict__ offs, int* __restrict__ pos) {
    __shared__ int s[1024];
    int g = blockIdx.x * 1024 + threadIdx.x;
    int v = (g < SCAN_N) ? deg[g] : 0;
    s[threadIdx.x] = v;
    __syncthreads();
    for (int off = 1; off < 1024; off <<= 1) {
        int t = (threadIdx.x >= off) ? s[threadIdx.x - off] : 0;
        __syncthreads();
        s[threadIdx.x] += t;
        __syncthreads();
    }
    int excl = s[threadIdx.x] - v + part[blockIdx.x];
    if (g < SCAN_N) { offs[g] = excl; pos[g] = excl; }
}

// ---------------------------------------------------------------------------
// Permute: counting-sort edges by dst; pack {src, dst, sqd} per slot.
// ---------------------------------------------------------------------------
__global__ __launch_bounds__(256) void permute_kernel(
    const void* __restrict__ feat, const void* __restrict__ xpos,
    const int* __restrict__ src, const int* __restrict__ dst,
    int* __restrict__ pos, uint4* __restrict__ epack)
{
    const int isb = detect_is_bf16((const unsigned short*)feat);
    int e = blockIdx.x * 256 + threadIdx.x;
    if (e < N_EDGES) {
        int s = src[e], d = dst[e];
        int slot = atomicAdd(&pos[d], 1);
        float dx = getf(xpos, s * 3 + 0, isb) - getf(xpos, d * 3 + 0, isb);
        float dy = getf(xpos, s * 3 + 1, isb) - getf(xpos, d * 3 + 1, isb);
        float dz = getf(xpos, s * 3 + 2, isb) - getf(xpos, d * 3 + 2, isb);
        float sqd = dx * dx + dy * dy + dz * dz;
        uint4 p;
        p.x = (unsigned int)s;
        p.y = (unsigned int)d;
        p.z = __float_as_uint(sqd);
        p.w = 0u;
        epack[slot] = p;
    }
}

// ---------------------------------------------------------------------------
// Edge kernel, 512 threads, dual-tile ILP, SINGLE-buffered per-wave sA2
// (LDS 42KB -> 3 blocks/CU), hw bf16 converts. In-register segmented
// reduce -> one coalesced 64-lane f32 atomic per dst segment.
// ---------------------------------------------------------------------------
template <bool CSR>
__global__ __launch_bounds__(512, 6) void edge_kernel(
    const unsigned short* __restrict__ fbf,
    const unsigned short* __restrict__ w1t, const unsigned short* __restrict__ w2t,
    const float* __restrict__ cst,
    const void* __restrict__ feat, const void* __restrict__ xpos,
    const int* __restrict__ src, const int* __restrict__ dst,
    const uint4* __restrict__ epack,
    const void* __restrict__ W1, const void* __restrict__ b1,
    const void* __restrict__ W2, const void* __restrict__ b2,
    const void* __restrict__ we, const void* __restrict__ be,
    float* __restrict__ msum, unsigned int msum_cap)
{
    __shared__ __align__(16) short sW1[16][64][8];   // frag f=c*4+nt, lane, 16B
    __shared__ __align__(16) short sW2[8][64][8];
    __shared__ __align__(16) short sA2[8][16][72];   // single per-wave tile buffer

    const int tid  = threadIdx.x;
    const int wave = tid >> 6;
    const int lane = tid & 63;
    const int l15  = lane & 15;
    const int quad = lane >> 4;
    const int rowb = quad * 4;

    float b1r[4], w1lr[4], b2r[4], wer[4];
    float ber;
    short8 bw1[4][4];    // fallback-only
    short8 bw2[2][4];

    if constexpr (CSR) {
        for (int i = tid; i < 16 * 64; i += 512) {
            int f = i >> 6, l = i & 63;
            int n = (f & 3) * 16 + (l & 15);
            int k0 = (f >> 2) * 32 + (l >> 4) * 8;
            *reinterpret_cast<short8*>(&sW1[f][l][0]) =
                *reinterpret_cast<const short8*>(w1t + n * 128 + k0);
        }
        for (int i = tid; i < 8 * 64; i += 512) {
            int f = i >> 6, l = i & 63;
            int n = (f & 3) * 16 + (l & 15);
            int k0 = (f >> 2) * 32 + (l >> 4) * 8;
            *reinterpret_cast<short8*>(&sW2[f][l][0]) =
                *reinterpret_cast<const short8*>(w2t + n * 64 + k0);
        }
        #pragma unroll
        for (int nt = 0; nt < 4; ++nt) {
            int n = nt * 16 + l15;
            b1r[nt]  = cst[n];
            w1lr[nt] = cst[64 + n];
            b2r[nt]  = cst[128 + n];
            wer[nt]  = cst[192 + n];
        }
        ber = cst[256];
        __syncthreads();

        const int nbiter = N_EDGES / 256;    // 3125
        for (int it = blockIdx.x; it < nbiter; it += gridDim.x) {
            const int ebase = it * 256 + wave * 16;

            int sidx = 0, didx = 0;
            float sqd = 0.f;
            if (lane < 32) {
                int e = ebase + l15 + ((lane >> 4) << 7);   // lanes 16-31: +128
                uint4 p = epack[e];
                sidx = (int)p.x;
                didx = (int)p.y;
                sqd  = __uint_as_float(p.z);
            }
            const int snA = __shfl(sidx, l15);
            const int dnA = __shfl(didx, l15);
            const int snB = __shfl(sidx, l15 + 16);
            const int dnB = __shfl(didx, l15 + 16);

            // ---- gathers for both tiles (8 independent loads in flight) ----
            short8 caA[4], caB[4];
            #pragma unroll
            for (int c = 0; c < 4; ++c) {
                const int nA = (c < 2) ? snA : dnA;
                const int nB = (c < 2) ? snB : dnB;
                caA[c] = *reinterpret_cast<const short8*>(
                    (const short*)fbf + (unsigned int)nA * 64u + (c & 1) * 32 + quad * 8);
                caB[c] = *reinterpret_cast<const short8*>(
                    (const short*)fbf + (unsigned int)nB * 64u + (c & 1) * 32 + quad * 8);
            }

            // ---- layer 1 (both tiles, shared B frags) ----
            floatx4 accA[4], accB[4];
            #pragma unroll
            for (int nt = 0; nt < 4; ++nt) {
                accA[nt] = (floatx4){0.f, 0.f, 0.f, 0.f};
                accB[nt] = (floatx4){0.f, 0.f, 0.f, 0.f};
            }
            #pragma unroll
            for (int c = 0; c < 4; ++c) {
                #pragma unroll
                for (int nt = 0; nt < 4; ++nt) {
                    short8 wb = *reinterpret_cast<const short8*>(&sW1[c * 4 + nt][lane][0]);
                    accA[nt] = __builtin_amdgcn_mfma_f32_16x16x32_bf16(caA[c], wb, accA[nt], 0, 0, 0);
                    accB[nt] = __builtin_amdgcn_mfma_f32_16x16x32_bf16(caB[c], wb, accB[nt], 0, 0, 0);
                }
            }

            float sqA[4], sqB[4];
            #pragma unroll
            for (int r = 0; r < 4; ++r) {
                sqA[r] = __shfl(sqd, rowb + r);
                sqB[r] = __shfl(sqd, 16 + rowb + r);
            }

            // ======== tile A: epi1 -> LDS -> layer2 ========
            #pragma unroll
            for (int nt = 0; nt < 4; ++nt)
                #pragma unroll
                for (int r = 0; r < 4; ++r) {
                    float vA = fmaxf(fmaf(sqA[r], w1lr[nt], accA[nt][r]) + b1r[nt], 0.f);
                    sA2[wave][rowb + r][nt * 16 + l15] = (short)f2bf_fast(vA);
                }
            COMPILER_FENCE();
            WAIT_LDS();

            floatx4 acc2A[4];
            #pragma unroll
            for (int nt = 0; nt < 4; ++nt) acc2A[nt] = (floatx4){0.f, 0.f, 0.f, 0.f};
            #pragma unroll
            for (int c = 0; c < 2; ++c) {
                short8 aA = *reinterpret_cast<const short8*>(&sA2[wave][l15][c * 32 + quad * 8]);
                #pragma unroll
                for (int nt = 0; nt < 4; ++nt) {
                    short8 wb = *reinterpret_cast<const short8*>(&sW2[c * 4 + nt][lane][0]);
                    acc2A[nt] = __builtin_amdgcn_mfma_f32_16x16x32_bf16(aA, wb, acc2A[nt], 0, 0, 0);
                }
            }
            COMPILER_FENCE();
            WAIT_LDS();     // aA reads complete before B overwrites the buffer

            // ======== tile B: epi1 -> LDS (overwrite) -> layer2 ========
            #pragma unroll
            for (int nt = 0; nt < 4; ++nt)
                #pragma unroll
                for (int r = 0; r < 4; ++r) {
                    float vB = fmaxf(fmaf(sqB[r], w1lr[nt], accB[nt][r]) + b1r[nt], 0.f);
                    sA2[wave][rowb + r][nt * 16 + l15] = (short)f2bf_fast(vB);
                }
            COMPILER_FENCE();
            WAIT_LDS();

            floatx4 acc2B[4];
            #pragma unroll
            for (int nt = 0; nt < 4; ++nt) acc2B[nt] = (floatx4){0.f, 0.f, 0.f, 0.f};
            #pragma unroll
            for (int c = 0; c < 2; ++c) {
                short8 aB = *reinterpret_cast<const short8*>(&sA2[wave][l15][c * 32 + quad * 8]);
                #pragma unroll
                for (int nt = 0; nt < 4; ++nt) {
                    short8 wb = *reinterpret_cast<const short8*>(&sW2[c * 4 + nt][lane][0]);
                    acc2B[nt] = __builtin_amdgcn_mfma_f32_16x16x32_bf16(aB, wb, acc2B[nt], 0, 0, 0);
                }
            }
            COMPILER_FENCE();

            // ---- epilogue 2: relu, gate (both tiles) ----
            float mvA[4][4], mvB[4][4];
            float pA[4] = {0.f, 0.f, 0.f, 0.f};
            float pB[4] = {0.f, 0.f, 0.f, 0.f};
            #pragma unroll
            for (int nt = 0; nt < 4; ++nt)
                #pragma unroll
                for (int r = 0; r < 4; ++r) {
                    float vA = fmaxf(acc2A[nt][r] + b2r[nt], 0.f);
                    float vB = fmaxf(acc2B[nt][r] + b2r[nt], 0.f);
                    mvA[nt][r] = vA;
                    mvB[nt][r] = vB;
                    pA[r] = fmaf(vA, wer[nt], pA[r]);
                    pB[r] = fmaf(vB, wer[nt], pB[r]);
                }
            #pragma unroll
            for (int off = 1; off < 16; off <<= 1)
                #pragma unroll
                for (int r = 0; r < 4; ++r) {
                    pA[r] += __shfl_xor(pA[r], off);
                    pB[r] += __shfl_xor(pB[r], off);
                }
            float gA[4], gB[4];
            #pragma unroll
            for (int r = 0; r < 4; ++r) {
                gA[r] = 1.f / (1.f + __expf(-(pA[r] + ber)));
                gB[r] = 1.f / (1.f + __expf(-(pB[r] + ber)));
            }

            // ---- in-register segmented reduce (both tiles) ----
            int grp = (lane >> 4) & 1;
            int nd = __shfl(didx, grp * 16 + ((l15 + 1) & 15));
            int flag = (lane < 32) && ((l15 == 15) || (nd != didx));
            unsigned long long bal = __ballot(flag);
            unsigned int mA = (unsigned int)(bal & 0xFFFFull);
            unsigned int mB = (unsigned int)((bal >> 16) & 0xFFFFull);

            int lo = 0;
            while (mA) {
                int hi = __ffs(mA) - 1;
                float s0 = 0.f, s1 = 0.f, s2 = 0.f, s3 = 0.f;
                #pragma unroll
                for (int r = 0; r < 4; ++r) {
                    int gr = rowb + r;
                    float g = (gr >= lo && gr <= hi) ? gA[r] : 0.f;
                    s0 = fmaf(g, mvA[0][r], s0);
                    s1 = fmaf(g, mvA[1][r], s1);
                    s2 = fmaf(g, mvA[2][r], s2);
                    s3 = fmaf(g, mvA[3][r], s3);
                }
                s0 += __shfl_xor(s0, 16); s0 += __shfl_xor(s0, 32);
                s1 += __shfl_xor(s1, 16); s1 += __shfl_xor(s1, 32);
                s2 += __shfl_xor(s2, 16); s2 += __shfl_xor(s2, 32);
                s3 += __shfl_xor(s3, 16); s3 += __shfl_xor(s3, 32);
                int d = __shfl(didx, hi);
                float v = (quad == 0) ? s0 : (quad == 1) ? s1 : (quad == 2) ? s2 : s3;
                unsafeAtomicAdd(&msum[(unsigned int)d * 64u + (unsigned int)quad * 16u + l15], v);
                lo = hi + 1;
                mA &= mA - 1;
            }
            lo = 0;
            while (mB) {
                int hi = __ffs(mB) - 1;
                float s0 = 0.f, s1 = 0.f, s2 = 0.f, s3 = 0.f;
                #pragma unroll
                for (int r = 0; r < 4; ++r) {
                    int gr = rowb + r;
                    float g = (gr >= lo && gr <= hi) ? gB[r] : 0.f;
                    s0 = fmaf(g, mvB[0][r], s0);
                    s1 = fmaf(g, mvB[1][r], s1);
                    s2 = fmaf(g, mvB[2][r], s2);
                    s3 = fmaf(g, mvB[3][r], s3);
                }
                s0 += __shfl_xor(s0, 16); s0 += __shfl_xor(s0, 32);
                s1 += __shfl_xor(s1, 16); s1 += __shfl_xor(s1, 32);
                s2 += __shfl_xor(s2, 16); s2 += __shfl_xor(s2, 32);
                s3 += __shfl_xor(s3, 16); s3 += __shfl_xor(s3, 32);
                int d = __shfl(didx, 16 + hi);
                float v = (quad == 0) ? s0 : (quad == 1) ? s1 : (quad == 2) ? s2 : s3;
                unsafeAtomicAdd(&msum[(unsigned int)d * 64u + (unsigned int)quad * 16u + l15], v);
                lo = hi + 1;
                mB &= mB - 1;
            }
        }
    } else {
        // ---------------- fallback path (no workspace) ----------------
        const int isb = detect_is_bf16((const unsigned short*)feat);
        #pragma unroll
        for (int c = 0; c < 4; ++c)
            #pragma unroll
            for (int nt = 0; nt < 4; ++nt) {
                short8 b;
                #pragma unroll
                for (int j = 0; j < 8; ++j)
                    b[j] = (short)f2bf(getf(W1, (c * 32 + quad * 8 + j) * 64 + nt * 16 + l15, isb));
                bw1[c][nt] = b;
            }
        #pragma unroll
        for (int c = 0; c < 2; ++c)
            #pragma unroll
            for (int nt = 0; nt < 4; ++nt) {
                short8 b;
                #pragma unroll
                for (int j = 0; j < 8; ++j)
                    b[j] = (short)f2bf(getf(W2, (c * 32 + quad * 8 + j) * 64 + nt * 16 + l15, isb));
                bw2[c][nt] = b;
            }
        #pragma unroll
        for (int nt = 0; nt < 4; ++nt) {
            int n = nt * 16 + l15;
            b1r[nt]  = getf(b1, n, isb);
            w1lr[nt] = getf(W1, 128 * 64 + n, isb);
            b2r[nt]  = getf(b2, n, isb);
            wer[nt]  = getf(we, n, isb);
        }
        ber = getf(be, 0, isb);

        const int ntiles = N_EDGES / 128;
        for (int t = blockIdx.x; t < ntiles; t += gridDim.x) {
            const int ebase = t * 128 + wave * 16;
            int sidx = 0, didx = 0;
            float sqd = 0.f;
            if (lane < 16) {
                int e = ebase + lane;
                sidx = src[e];
                didx = dst[e];
                float dx = getf(xpos, sidx * 3 + 0, isb) - getf(xpos, didx * 3 + 0, isb);
                float dy = getf(xpos, sidx * 3 + 1, isb) - getf(xpos, didx * 3 + 1, isb);
                float dz = getf(xpos, sidx * 3 + 2, isb) - getf(xpos, didx * 3 + 2, isb);
                sqd = dx * dx + dy * dy + dz * dz;
            }
            const int sn     = __shfl(sidx, l15);
            const int dn_row = __shfl(didx, l15);

            floatx4 acc[4];
            #pragma unroll
            for (int nt = 0; nt < 4; ++nt) acc[nt] = (floatx4){0.f, 0.f, 0.f, 0.f};
            #pragma unroll
            for (int c = 0; c < 4; ++c) {
                const int node = (c < 2) ? sn : dn_row;
                const unsigned int aoff = (unsigned int)node * 64u + (c & 1) * 32 + quad * 8;
                short8 a = get8bf(feat, aoff, isb);
                #pragma unroll
                for (int nt = 0; nt < 4; ++nt)
                    acc[nt] = __builtin_amdgcn_mfma_f32_16x16x32_bf16(a, bw1[c][nt], acc[nt], 0, 0, 0);
            }

            float sq[4];
            #pragma unroll
            for (int r = 0; r < 4; ++r) sq[r] = __shfl(sqd, rowb + r);
            #pragma unroll
            for (int nt = 0; nt < 4; ++nt)
                #pragma unroll
                for (int r = 0; r < 4; ++r) {
                    float v = fmaxf(acc[nt][r] + b1r[nt] + sq[r] * w1lr[nt], 0.f);
                    sA2[wave][rowb + r][nt * 16 + l15] = (short)f2bf(v);
                }
            COMPILER_FENCE();
            WAIT_LDS();

            floatx4 acc2[4];
            #pragma unroll
            for (int nt = 0; nt < 4; ++nt) acc2[nt] = (floatx4){0.f, 0.f, 0.f, 0.f};
            #pragma unroll
            for (int c = 0; c < 2; ++c) {
                short8 a = *reinterpret_cast<const short8*>(&sA2[wave][l15][c * 32 + quad * 8]);
                #pragma unroll
                for (int nt = 0; nt < 4; ++nt)
                    acc2[nt] = __builtin_amdgcn_mfma_f32_16x16x32_bf16(a, bw2[c][nt], acc2[nt], 0, 0, 0);
            }
            COMPILER_FENCE();
            WAIT_LDS();

            float mval[4][4];
            float part[4] = {0.f, 0.f, 0.f, 0.f};
            #pragma unroll
            for (int nt = 0; nt < 4; ++nt)
                #pragma unroll
                for (int r = 0; r < 4; ++r) {
                    float v = fmaxf(acc2[nt][r] + b2r[nt], 0.f);
                    mval[nt][r] = v;
                    part[r] += v * wer[nt];
                }
            #pragma unroll
            for (int off = 1; off < 16; off <<= 1)
                #pragma unroll
                for (int r = 0; r < 4; ++r) part[r] += __shfl_xor(part[r], off);
            float gate[4];
            #pragma unroll
            for (int r = 0; r < 4; ++r)
                gate[r] = 1.f / (1.f + __expf(-(part[r] + ber)));

            #pragma unroll
            for (int r = 0; r < 4; ++r) {
                int dn = __shfl(didx, rowb + r);
                unsigned int base = (unsigned int)dn * 64u;
                if (base + 64u <= msum_cap) {
                    #pragma unroll
                    for (int nt = 0; nt < 4; ++nt)
                        unsafeAtomicAdd(&msum[base + nt * 16 + l15], mval[nt][r] * gate[r]);
                }
            }
        }
    }
}

// ---------------------------------------------------------------------------
// Node kernel: per wave a 16-node MFMA M-tile; reads f32 msum directly.
// ---------------------------------------------------------------------------
__global__ __launch_bounds__(256, 2) void node_kernel(
    const float* __restrict__ msum,
    const unsigned short* __restrict__ u1t, const unsigned short* __restrict__ u2t,
    const void* __restrict__ feat,
    const void* __restrict__ U1, const void* __restrict__ c1v,
    const void* __restrict__ U2, const void* __restrict__ c2v,
    void* __restrict__ out)
{
    __shared__ __align__(16) short sT[4][16][72];
    __shared__ __align__(16) float sF[4][16][68];

    const int isb  = detect_is_bf16((const unsigned short*)feat);
    const int tid  = threadIdx.x;
    const int wave = tid >> 6;
    const int lane = tid & 63;
    const int l15  = lane & 15;
    const int quad = lane >> 4;

    short8 u1f[2][4], u2f[2][4];
    if (u1t) {
        #pragma unroll
        for (int nt = 0; nt < 4; ++nt) {
            const int n = nt * 16 + l15;
            #pragma unroll
            for (int c = 0; c < 2; ++c) {
                u1f[c][nt] = *reinterpret_cast<const short8*>(u1t + n * 64 + c * 32 + quad * 8);
                u2f[c][nt] = *reinterpret_cast<const short8*>(u2t + n * 64 + c * 32 + quad * 8);
            }
        }
    } else {
        #pragma unroll
        for (int c = 0; c < 2; ++c)
            #pragma unroll
            for (int nt = 0; nt < 4; ++nt) {
                short8 a, b;
                #pragma unroll
                for (int j = 0; j < 8; ++j) {
                    int k = c * 32 + quad * 8 + j, n = nt * 16 + l15;
                    a[j] = (short)f2bf(getf(U1, k * 64 + n, isb));
                    b[j] = (short)f2bf(getf(U2, k * 64 + n, isb));
                }
                u1f[c][nt] = a; u2f[c][nt] = b;
            }
    }
    float c1r[4], c2r[4];
    #pragma unroll
    for (int nt = 0; nt < 4; ++nt) {
        c1r[nt] = getf(c1v, nt * 16 + l15, isb);
        c2r[nt] = getf(c2v, nt * 16 + l15, isb);
    }
    const int rowb = quad * 4;

    const int ntile = (N_NODES + 15) / 16;   // 3125
    const int t = blockIdx.x * 4 + wave;
    if (t < ntile) {
        const int node = t * 16 + l15;

        // ---- message sum (f32 msum) + h fragments ----
        short8 ah[2];
        #pragma unroll
        for (int c = 0; c < 2; ++c) {
            unsigned int off = (unsigned int)node * 64u + c * 32 + quad * 8;
            float4 m0 = *reinterpret_cast<const float4*>(msum + off);
            float4 m1 = *reinterpret_cast<const float4*>(msum + off + 4);
            float mv[8] = {m0.x, m0.y, m0.z, m0.w, m1.x, m1.y, m1.z, m1.w};
            float hv[8];
            if (isb) {
                short8 fv = *reinterpret_cast<const short8*>((const short*)feat + off);
                #pragma unroll
                for (int j = 0; j < 8; ++j) hv[j] = bf2f((unsigned short)fv[j]);
            } else {
                float4 f0 = *reinterpret_cast<const float4*>((const float*)feat + off);
                float4 f1 = *reinterpret_cast<const float4*>((const float*)feat + off + 4);
                hv[0] = f0.x; hv[1] = f0.y; hv[2] = f0.z; hv[3] = f0.w;
                hv[4] = f1.x; hv[5] = f1.y; hv[6] = f1.z; hv[7] = f1.w;
            }
            short8 a;
            #pragma unroll
            for (int j = 0; j < 8; ++j) a[j] = (short)f2bf_fast(mv[j] + hv[j]);
            ah[c] = a;
        }

        // ---- layer 1: relu(h@U1+c1) ----
        floatx4 acc[4];
        #pragma unroll
        for (int nt = 0; nt < 4; ++nt) acc[nt] = (floatx4){0.f, 0.f, 0.f, 0.f};
        #pragma unroll
        for (int c = 0; c < 2; ++c)
            #pragma unroll
            for (int nt = 0; nt < 4; ++nt)
                acc[nt] = __builtin_amdgcn_mfma_f32_16x16x32_bf16(ah[c], u1f[c][nt], acc[nt], 0, 0, 0);

        #pragma unroll
        for (int nt = 0; nt < 4; ++nt)
            #pragma unroll
            for (int r = 0; r < 4; ++r) {
                float v = fmaxf(acc[nt][r] + c1r[nt], 0.f);
                sT[wave][rowb + r][nt * 16 + l15] = (short)f2bf_fast(v);
            }
        COMPILER_FENCE();
        WAIT_LDS();

        // ---- layer 2 ----
        floatx4 acc2[4];
        #pragma unroll
        for (int nt = 0; nt < 4; ++nt) acc2[nt] = (floatx4){0.f, 0.f, 0.f, 0.f};
        #pragma unroll
        for (int c = 0; c < 2; ++c) {
            short8 a = *reinterpret_cast<const short8*>(&sT[wave][l15][c * 32 + quad * 8]);
            #pragma unroll
            for (int nt = 0; nt < 4; ++nt)
                acc2[nt] = __builtin_amdgcn_mfma_f32_16x16x32_bf16(a, u2f[c][nt], acc2[nt], 0, 0, 0);
        }
        COMPILER_FENCE();

        // ---- epilogue: D-layout -> f32 LDS -> row-coalesced (+feat) store ----
        #pragma unroll
        for (int nt = 0; nt < 4; ++nt)
            #pragma unroll
            for (int r = 0; r < 4; ++r)
                sF[wave][rowb + r][nt * 16 + l15] = acc2[nt][r] + c2r[nt];
        COMPILER_FENCE();
        WAIT_LDS();

        const unsigned int ob = (unsigned int)node * 64u + quad * 16;
        if (isb) {
            const unsigned short* fp = (const unsigned short*)feat + ob;
            unsigned short* op = (unsigned short*)out + ob;
            #pragma unroll
            for (int k = 0; k < 2; ++k) {
                ushort4 o0, o1;
                float4 v0 = *reinterpret_cast<const float4*>(&sF[wave][l15][quad * 16 + k * 8]);
                float4 v1 = *reinterpret_cast<const float4*>(&sF[wave][l15][quad * 16 + k * 8 + 4]);
                const ushort4 f0 = *reinterpret_cast<const ushort4*>(fp + k * 8);
                const ushort4 f1 = *reinterpret_cast<const ushort4*>(fp + k * 8 + 4);
                o0.x = f2bf_fast(v0.x + bf2f(f0.x)); o0.y = f2bf_fast(v0.y + bf2f(f0.y));
                o0.z = f2bf_fast(v0.z + bf2f(f0.z)); o0.w = f2bf_fast(v0.w + bf2f(f0.w));
                o1.x = f2bf_fast(v1.x + bf2f(f1.x)); o1.y = f2bf_fast(v1.y + bf2f(f1.y));
                o1.z = f2bf_fast(v1.z + bf2f(f1.z)); o1.w = f2bf_fast(v1.w + bf2f(f1.w));
                *reinterpret_cast<ushort4*>(op + k * 8)     = o0;
                *reinterpret_cast<ushort4*>(op + k * 8 + 4) = o1;
            }
        } else {
            const float* fp = (const float*)feat + ob;
            float* op = (float*)out + ob;
            #pragma unroll
            for (int k = 0; k < 4; ++k) {
                float4 v = *reinterpret_cast<const float4*>(&sF[wave][l15][quad * 16 + k * 4]);
                float4 f = *reinterpret_cast<const float4*>(fp + k * 4);
                float4 o = {v.x + f.x, v.y + f.y, v.z + f.z, v.w + f.w};
                *reinterpret_cast<float4*>(op + k * 4) = o;
            }
        }
        COMPILER_FENCE();
    }
}

extern "C" void kernel_launch(void* const* d_in, const int* in_sizes, int n_in,
                              void* d_out, int out_size, void* d_ws, size_t ws_size,
                              hipStream_t stream) {
    const void* feat = d_in[0];
    const void* x    = d_in[1];
    const int* src   = (const int*)d_in[2];
    const int* dst   = (const int*)d_in[3];
    const void* W1   = d_in[4];
    const void* b1   = d_in[5];
    const void* W2   = d_in[6];
    const void* b2   = d_in[7];
    const void* we   = d_in[8];
    const void* be   = d_in[9];
    const void* U1   = d_in[10];
    const void* c1   = d_in[11];
    const void* U2   = d_in[12];
    const void* c2   = d_in[13];
    char* ws = (char*)d_ws;

    if (ws_size >= WS_NEED) {
        float* msum = (float*)(ws + MSUM_OFF);
        uint4* epack = (uint4*)(ws + EP_OFF);
        int* deg  = (int*)(ws + DEG_OFF);
        int* offs = (int*)(ws + OFFS_OFF);
        int* pos  = (int*)(ws + POS_OFF);
        unsigned short* fb  = (unsigned short*)(ws + FB_OFF);
        unsigned short* w1t = (unsigned short*)(ws + W1T_OFF);
        unsigned short* w2t = (unsigned short*)(ws + W2T_OFF);
        unsigned short* u1t = (unsigned short*)(ws + U1T_OFF);
        unsigned short* u2t = (unsigned short*)(ws + U2T_OFF);
        float* cst = (float*)(ws + CST_OFF);

        hipMemsetAsync(deg, 0, 204800, stream);
        prep_kernel<<<CVT_BLOCKS + PREPW_BLOCKS + MZ_BLOCKS + HIST_BLOCKS, 256, 0, stream>>>(
            feat, fb, W1, W2, U1, U2, b1, b2, we, be,
            w1t, w2t, u1t, u2t, cst, dst, deg, (uint4*)msum);
        scan1_kernel<<<49, 1024, 0, stream>>>(deg, offs + 51200 - 64);
        scan2_kernel<<<1, 64, 0, stream>>>(offs + 51200 - 64, 49);
        scan3_kernel<<<49, 1024, 0, stream>>>(deg, offs + 51200 - 64, offs, pos);
        permute_kernel<<<(N_EDGES + 255) / 256, 256, 0, stream>>>(feat, x, src, dst, pos, epack);
        edge_kernel<true><<<768, 512, 0, stream>>>(fb, w1t, w2t, cst, feat, x, src, dst, epack,
                                                   W1, b1, W2, b2, we, be,
                                                   msum, (unsigned int)(N_NODES * HDIM));
        node_kernel<<<((N_NODES + 15) / 16 + 3) / 4, 256, 0, stream>>>(
            msum, u1t, u2t, feat, U1, c1, U2, c2, d_out);
    } else {
        float* msum = (float*)ws;
        size_t need = (size_t)N_NODES * HDIM * sizeof(float);
        size_t clr  = need < ws_size ? need : ws_size;
        unsigned int cap = (unsigned int)(ws_size / sizeof(float));
        if (cap > (unsigned int)(N_NODES * HDIM)) cap = (unsigned int)(N_NODES * HDIM);

        hipMemsetAsync(msum, 0, clr, stream);
        edge_kernel<false><<<1250, 512, 0, stream>>>(nullptr, nullptr, nullptr, nullptr,
                                                     feat, x, src, dst,
                                                     nullptr, W1, b1, W2, b2, we, be,
                                                     msum, cap);
        node_kernel<<<((N_NODES + 15) / 16 + 3) / 4, 256, 0, stream>>>(
            msum, nullptr, nullptr, feat, U1, c1, U2, c2, d_out);
    }
}

// Round 7
// 268.827 us; speedup vs baseline: 1.1010x; 1.0281x over previous
//
#include <hip/hip_runtime.h>
#include <hip/hip_bf16.h>
#include <stdint.h>

#define N_NODES 50000
#define N_EDGES 800000
#define HDIM 64
#define SCAN_N (N_NODES + 1)

// ---- workspace layout (CSR path) ----
#define MSUM_OFF   0                                  // 50000*64*4 = 12.8 MB f32
#define EP_OFF     12800000                           // 800000*16 B packed edges
#define DEG_OFF    (EP_OFF + 12800000)
#define OFFS_OFF   (DEG_OFF + 204800)
#define POS_OFF    (OFFS_OFF + 204800)
#define FB_OFF     (POS_OFF + 204800)
#define W1T_OFF    (FB_OFF + (size_t)N_NODES * HDIM * 2)
#define W2T_OFF    (W1T_OFF + 16384)
#define U1T_OFF    (W2T_OFF + 8192)
#define U2T_OFF    (U1T_OFF + 8192)
#define CST_OFF    (U2T_OFF + 8192)
#define WS_NEED    (CST_OFF + 4096)

// fused prep kernel block ranges
#define CVT_BLOCKS   1563             // ceil(3.2M/8/256) feat->bf16
#define PREPW_BLOCKS 82               // transposed weights + consts
#define MZ_BLOCKS    3125             // msum zero: 12.8MB / (256*16B)
#define HIST_BLOCKS  1024             // dst histogram

typedef __attribute__((ext_vector_type(8))) short short8;
typedef __attribute__((ext_vector_type(4))) float floatx4;

__device__ __forceinline__ float bf2f(unsigned short u) {
    union { unsigned int i; float f; } v; v.i = ((unsigned int)u) << 16; return v.f;
}
__device__ __forceinline__ unsigned short f2bf(float f) {
    __hip_bfloat16 h = __float2bfloat16(f);
    return *reinterpret_cast<unsigned short*>(&h);
}

__device__ __forceinline__ int detect_is_bf16(const unsigned short* p) {
    int cnt = 0;
    #pragma unroll
    for (int i = 0; i < 64; ++i) {
        unsigned short b = p[i];
        int e = (b >> 7) & 0xFF;
        cnt += ((e >= 97 && e <= 157) || (b & 0x7FFF) == 0) ? 1 : 0;
    }
    return cnt >= 56;
}

__device__ __forceinline__ float getf(const void* p, unsigned int i, int isb) {
    return isb ? bf2f(((const unsigned short*)p)[i]) : ((const float*)p)[i];
}

__device__ __forceinline__ short8 get8bf(const void* p, unsigned int i, int isb) {
    if (isb) {
        return *reinterpret_cast<const short8*>((const short*)p + i);
    } else {
        const float4 f0 = *reinterpret_cast<const float4*>((const float*)p + i);
        const float4 f1 = *reinterpret_cast<const float4*>((const float*)p + i + 4);
        short8 a;
        a[0] = (short)f2bf(f0.x); a[1] = (short)f2bf(f0.y);
        a[2] = (short)f2bf(f0.z); a[3] = (short)f2bf(f0.w);
        a[4] = (short)f2bf(f1.x); a[5] = (short)f2bf(f1.y);
        a[6] = (short)f2bf(f1.z); a[7] = (short)f2bf(f1.w);
        return a;
    }
}

#define COMPILER_FENCE() asm volatile("" ::: "memory")
#define WAIT_LDS() __builtin_amdgcn_s_waitcnt(0xC07F)   // lgkmcnt(0) only

// ---------------------------------------------------------------------------
// Fused prep: feat->bf16 | transposed weights + f32 consts | msum zero | hist
// ---------------------------------------------------------------------------
__global__ __launch_bounds__(256) void prep_kernel(
    const void* __restrict__ feat, unsigned short* __restrict__ fb,
    const void* __restrict__ W1, const void* __restrict__ W2,
    const void* __restrict__ U1, const void* __restrict__ U2,
    const void* __restrict__ b1, const void* __restrict__ b2,
    const void* __restrict__ we, const void* __restrict__ be,
    unsigned short* __restrict__ w1t, unsigned short* __restrict__ w2t,
    unsigned short* __restrict__ u1t, unsigned short* __restrict__ u2t,
    float* __restrict__ cst,
    const int* __restrict__ dst, int* __restrict__ deg,
    uint4* __restrict__ msumz)
{
    const int b = blockIdx.x;
    if (b < CVT_BLOCKS) {
        const int isb = detect_is_bf16((const unsigned short*)feat);
        int i = (b * 256 + threadIdx.x) * 8;
        if (i >= N_NODES * HDIM) return;
        if (isb) {
            *reinterpret_cast<uint4*>(fb + i) =
                *reinterpret_cast<const uint4*>((const unsigned short*)feat + i);
        } else {
            float4 f0 = *reinterpret_cast<const float4*>((const float*)feat + i);
            float4 f1 = *reinterpret_cast<const float4*>((const float*)feat + i + 4);
            ushort4 a = {f2bf(f0.x), f2bf(f0.y), f2bf(f0.z), f2bf(f0.w)};
            ushort4 c = {f2bf(f1.x), f2bf(f1.y), f2bf(f1.z), f2bf(f1.w)};
            *reinterpret_cast<ushort4*>(fb + i)     = a;
            *reinterpret_cast<ushort4*>(fb + i + 4) = c;
        }
    } else if (b < CVT_BLOCKS + PREPW_BLOCKS) {
        const int isb = detect_is_bf16((const unsigned short*)feat);
        int idx = (b - CVT_BLOCKS) * 256 + threadIdx.x;
        if (idx < 8192) {                               // W1T [64][128]
            int n = idx >> 7, k = idx & 127;
            w1t[idx] = f2bf(getf(W1, k * 64 + n, isb));
        } else if (idx < 12288) {                       // W2T [64][64]
            int i = idx - 8192, n = i >> 6, k = i & 63;
            w2t[i] = f2bf(getf(W2, k * 64 + n, isb));
        } else if (idx < 16384) {                       // U1T
            int i = idx - 12288, n = i >> 6, k = i & 63;
            u1t[i] = f2bf(getf(U1, k * 64 + n, isb));
        } else if (idx < 20480) {                       // U2T
            int i = idx - 16384, n = i >> 6, k = i & 63;
            u2t[i] = f2bf(getf(U2, k * 64 + n, isb));
        } else if (idx < 20737) {                       // f32 consts table
            int i = idx - 20480;
            float v;
            if (i < 64)       v = getf(b1, i, isb);
            else if (i < 128) v = getf(W1, 128 * 64 + (i - 64), isb);   // sqd row
            else if (i < 192) v = getf(b2, i - 128, isb);
            else if (i < 256) v = getf(we, i - 192, isb);
            else              v = getf(be, 0, isb);
            cst[i] = v;
        }
    } else if (b < CVT_BLOCKS + PREPW_BLOCKS + MZ_BLOCKS) {
        int i = (b - CVT_BLOCKS - PREPW_BLOCKS) * 256 + threadIdx.x;
        if (i < N_NODES * HDIM / 4)
            msumz[i] = (uint4){0u, 0u, 0u, 0u};
    } else {
        int e0 = (b - CVT_BLOCKS - PREPW_BLOCKS - MZ_BLOCKS) * 256 + threadIdx.x;
        for (int e = e0; e < N_EDGES; e += HIST_BLOCKS * 256)
            atomicAdd(&deg[dst[e]], 1);
    }
}

// ---------------------------------------------------------------------------
// CSR scan (multi-block, proven — fused variants regressed twice)
// ---------------------------------------------------------------------------
__global__ void scan1_kernel(const int* __restrict__ deg, int* __restrict__ part) {
    __shared__ int s[1024];
    int g = blockIdx.x * 1024 + threadIdx.x;
    s[threadIdx.x] = (g < SCAN_N) ? deg[g] : 0;
    __syncthreads();
    for (int off = 512; off > 0; off >>= 1) {
        if (threadIdx.x < off) s[threadIdx.x] += s[threadIdx.x + off];
        __syncthreads();
    }
    if (threadIdx.x == 0) part[blockIdx.x] = s[0];
}

__global__ void scan2_kernel(int* __restrict__ part, int nparts) {
    if (threadIdx.x == 0) {
        int run = 0;
        for (int i = 0; i < nparts; ++i) { int t = part[i]; part[i] = run; run += t; }
    }
}

__global__ void scan3_kernel(const int* __restrict__ deg, const int* __restrict__ part,
                             int* __restrict__ offs, int* __restrict__ pos) {
    __shared__ int s[1024];
    int g = blockIdx.x * 1024 + threadIdx.x;
    int v = (g < SCAN_N) ? deg[g] : 0;
    s[threadIdx.x] = v;
    __syncthreads();
    for (int off = 1; off < 1024; off <<= 1) {
        int t = (threadIdx.x >= off) ? s[threadIdx.x - off] : 0;
        __syncthreads();
        s[threadIdx.x] += t;
        __syncthreads();
    }
    int excl = s[threadIdx.x] - v + part[blockIdx.x];
    if (g < SCAN_N) { offs[g] = excl; pos[g] = excl; }
}

// ---------------------------------------------------------------------------
// Permute: counting-sort edges by dst; pack {src, dst, sqd} per slot.
// ---------------------------------------------------------------------------
__global__ __launch_bounds__(256) void permute_kernel(
    const void* __restrict__ feat, const void* __restrict__ xpos,
    const int* __restrict__ src, const int* __restrict__ dst,
    int* __restrict__ pos, uint4* __restrict__ epack)
{
    const int isb = detect_is_bf16((const unsigned short*)feat);
    int e = blockIdx.x * 256 + threadIdx.x;
    if (e < N_EDGES) {
        int s = src[e], d = dst[e];
        int slot = atomicAdd(&pos[d], 1);
        float dx = getf(xpos, s * 3 + 0, isb) - getf(xpos, d * 3 + 0, isb);
        float dy = getf(xpos, s * 3 + 1, isb) - getf(xpos, d * 3 + 1, isb);
        float dz = getf(xpos, s * 3 + 2, isb) - getf(xpos, d * 3 + 2, isb);
        float sqd = dx * dx + dy * dy + dz * dz;
        uint4 p;
        p.x = (unsigned int)s;
        p.y = (unsigned int)d;
        p.z = __float_as_uint(sqd);
        p.w = 0u;
        epack[slot] = p;
    }
}

// ---------------------------------------------------------------------------
// Edge kernel, 512 threads, dual-tile ILP, single-buffered per-wave sA2
// (LDS 42KB -> 3 blocks/CU). launch_bounds (512,4): r6's (512,6) caused
// VGPR spill (+165MB HBM scratch traffic). In-register segmented reduce ->
// one coalesced 64-lane f32 atomic per dst segment.
// ---------------------------------------------------------------------------
template <bool CSR>
__global__ __launch_bounds__(512, 4) void edge_kernel(
    const unsigned short* __restrict__ fbf,
    const unsigned short* __restrict__ w1t, const unsigned short* __restrict__ w2t,
    const float* __restrict__ cst,
    const void* __restrict__ feat, const void* __restrict__ xpos,
    const int* __restrict__ src, const int* __restrict__ dst,
    const uint4* __restrict__ epack,
    const void* __restrict__ W1, const void* __restrict__ b1,
    const void* __restrict__ W2, const void* __restrict__ b2,
    const void* __restrict__ we, const void* __restrict__ be,
    float* __restrict__ msum, unsigned int msum_cap)
{
    __shared__ __align__(16) short sW1[16][64][8];   // frag f=c*4+nt, lane, 16B
    __shared__ __align__(16) short sW2[8][64][8];
    __shared__ __align__(16) short sA2[8][16][72];   // single per-wave tile buffer

    const int tid  = threadIdx.x;
    const int wave = tid >> 6;
    const int lane = tid & 63;
    const int l15  = lane & 15;
    const int quad = lane >> 4;
    const int rowb = quad * 4;

    float b1r[4], w1lr[4], b2r[4], wer[4];
    float ber;
    short8 bw1[4][4];    // fallback-only
    short8 bw2[2][4];

    if constexpr (CSR) {
        for (int i = tid; i < 16 * 64; i += 512) {
            int f = i >> 6, l = i & 63;
            int n = (f & 3) * 16 + (l & 15);
            int k0 = (f >> 2) * 32 + (l >> 4) * 8;
            *reinterpret_cast<short8*>(&sW1[f][l][0]) =
                *reinterpret_cast<const short8*>(w1t + n * 128 + k0);
        }
        for (int i = tid; i < 8 * 64; i += 512) {
            int f = i >> 6, l = i & 63;
            int n = (f & 3) * 16 + (l & 15);
            int k0 = (f >> 2) * 32 + (l >> 4) * 8;
            *reinterpret_cast<short8*>(&sW2[f][l][0]) =
                *reinterpret_cast<const short8*>(w2t + n * 64 + k0);
        }
        #pragma unroll
        for (int nt = 0; nt < 4; ++nt) {
            int n = nt * 16 + l15;
            b1r[nt]  = cst[n];
            w1lr[nt] = cst[64 + n];
            b2r[nt]  = cst[128 + n];
            wer[nt]  = cst[192 + n];
        }
        ber = cst[256];
        __syncthreads();

        const int nbiter = N_EDGES / 256;    // 3125
        for (int it = blockIdx.x; it < nbiter; it += gridDim.x) {
            const int ebase = it * 256 + wave * 16;

            int sidx = 0, didx = 0;
            float sqd = 0.f;
            if (lane < 32) {
                int e = ebase + l15 + ((lane >> 4) << 7);   // lanes 16-31: +128
                uint4 p = epack[e];
                sidx = (int)p.x;
                didx = (int)p.y;
                sqd  = __uint_as_float(p.z);
            }
            const int snA = __shfl(sidx, l15);
            const int dnA = __shfl(didx, l15);
            const int snB = __shfl(sidx, l15 + 16);
            const int dnB = __shfl(didx, l15 + 16);

            // ---- gathers for both tiles (8 independent loads in flight) ----
            short8 caA[4], caB[4];
            #pragma unroll
            for (int c = 0; c < 4; ++c) {
                const int nA = (c < 2) ? snA : dnA;
                const int nB = (c < 2) ? snB : dnB;
                caA[c] = *reinterpret_cast<const short8*>(
                    (const short*)fbf + (unsigned int)nA * 64u + (c & 1) * 32 + quad * 8);
                caB[c] = *reinterpret_cast<const short8*>(
                    (const short*)fbf + (unsigned int)nB * 64u + (c & 1) * 32 + quad * 8);
            }

            // ---- layer 1 (both tiles, shared B frags) ----
            floatx4 accA[4], accB[4];
            #pragma unroll
            for (int nt = 0; nt < 4; ++nt) {
                accA[nt] = (floatx4){0.f, 0.f, 0.f, 0.f};
                accB[nt] = (floatx4){0.f, 0.f, 0.f, 0.f};
            }
            #pragma unroll
            for (int c = 0; c < 4; ++c) {
                #pragma unroll
                for (int nt = 0; nt < 4; ++nt) {
                    short8 wb = *reinterpret_cast<const short8*>(&sW1[c * 4 + nt][lane][0]);
                    accA[nt] = __builtin_amdgcn_mfma_f32_16x16x32_bf16(caA[c], wb, accA[nt], 0, 0, 0);
                    accB[nt] = __builtin_amdgcn_mfma_f32_16x16x32_bf16(caB[c], wb, accB[nt], 0, 0, 0);
                }
            }

            float sqA[4], sqB[4];
            #pragma unroll
            for (int r = 0; r < 4; ++r) {
                sqA[r] = __shfl(sqd, rowb + r);
                sqB[r] = __shfl(sqd, 16 + rowb + r);
            }

            // ======== tile A: epi1 -> LDS -> layer2 ========
            #pragma unroll
            for (int nt = 0; nt < 4; ++nt)
                #pragma unroll
                for (int r = 0; r < 4; ++r) {
                    float vA = fmaxf(fmaf(sqA[r], w1lr[nt], accA[nt][r]) + b1r[nt], 0.f);
                    sA2[wave][rowb + r][nt * 16 + l15] = (short)f2bf(vA);
                }
            COMPILER_FENCE();
            WAIT_LDS();

            floatx4 acc2A[4];
            #pragma unroll
            for (int nt = 0; nt < 4; ++nt) acc2A[nt] = (floatx4){0.f, 0.f, 0.f, 0.f};
            #pragma unroll
            for (int c = 0; c < 2; ++c) {
                short8 aA = *reinterpret_cast<const short8*>(&sA2[wave][l15][c * 32 + quad * 8]);
                #pragma unroll
                for (int nt = 0; nt < 4; ++nt) {
                    short8 wb = *reinterpret_cast<const short8*>(&sW2[c * 4 + nt][lane][0]);
                    acc2A[nt] = __builtin_amdgcn_mfma_f32_16x16x32_bf16(aA, wb, acc2A[nt], 0, 0, 0);
                }
            }
            COMPILER_FENCE();
            WAIT_LDS();     // aA reads complete before B overwrites the buffer

            // ======== tile B: epi1 -> LDS (overwrite) -> layer2 ========
            #pragma unroll
            for (int nt = 0; nt < 4; ++nt)
                #pragma unroll
                for (int r = 0; r < 4; ++r) {
                    float vB = fmaxf(fmaf(sqB[r], w1lr[nt], accB[nt][r]) + b1r[nt], 0.f);
                    sA2[wave][rowb + r][nt * 16 + l15] = (short)f2bf(vB);
                }
            COMPILER_FENCE();
            WAIT_LDS();

            floatx4 acc2B[4];
            #pragma unroll
            for (int nt = 0; nt < 4; ++nt) acc2B[nt] = (floatx4){0.f, 0.f, 0.f, 0.f};
            #pragma unroll
            for (int c = 0; c < 2; ++c) {
                short8 aB = *reinterpret_cast<const short8*>(&sA2[wave][l15][c * 32 + quad * 8]);
                #pragma unroll
                for (int nt = 0; nt < 4; ++nt) {
                    short8 wb = *reinterpret_cast<const short8*>(&sW2[c * 4 + nt][lane][0]);
                    acc2B[nt] = __builtin_amdgcn_mfma_f32_16x16x32_bf16(aB, wb, acc2B[nt], 0, 0, 0);
                }
            }
            COMPILER_FENCE();

            // ---- epilogue 2: relu, gate (both tiles) ----
            float mvA[4][4], mvB[4][4];
            float pA[4] = {0.f, 0.f, 0.f, 0.f};
            float pB[4] = {0.f, 0.f, 0.f, 0.f};
            #pragma unroll
            for (int nt = 0; nt < 4; ++nt)
                #pragma unroll
                for (int r = 0; r < 4; ++r) {
                    float vA = fmaxf(acc2A[nt][r] + b2r[nt], 0.f);
                    float vB = fmaxf(acc2B[nt][r] + b2r[nt], 0.f);
                    mvA[nt][r] = vA;
                    mvB[nt][r] = vB;
                    pA[r] = fmaf(vA, wer[nt], pA[r]);
                    pB[r] = fmaf(vB, wer[nt], pB[r]);
                }
            #pragma unroll
            for (int off = 1; off < 16; off <<= 1)
                #pragma unroll
                for (int r = 0; r < 4; ++r) {
                    pA[r] += __shfl_xor(pA[r], off);
                    pB[r] += __shfl_xor(pB[r], off);
                }
            float gA[4], gB[4];
            #pragma unroll
            for (int r = 0; r < 4; ++r) {
                gA[r] = 1.f / (1.f + __expf(-(pA[r] + ber)));
                gB[r] = 1.f / (1.f + __expf(-(pB[r] + ber)));
            }

            // ---- in-register segmented reduce (both tiles) ----
            int grp = (lane >> 4) & 1;
            int nd = __shfl(didx, grp * 16 + ((l15 + 1) & 15));
            int flag = (lane < 32) && ((l15 == 15) || (nd != didx));
            unsigned long long bal = __ballot(flag);
            unsigned int mA = (unsigned int)(bal & 0xFFFFull);
            unsigned int mB = (unsigned int)((bal >> 16) & 0xFFFFull);

            int lo = 0;
            while (mA) {
                int hi = __ffs(mA) - 1;
                float s0 = 0.f, s1 = 0.f, s2 = 0.f, s3 = 0.f;
                #pragma unroll
                for (int r = 0; r < 4; ++r) {
                    int gr = rowb + r;
                    float g = (gr >= lo && gr <= hi) ? gA[r] : 0.f;
                    s0 = fmaf(g, mvA[0][r], s0);
                    s1 = fmaf(g, mvA[1][r], s1);
                    s2 = fmaf(g, mvA[2][r], s2);
                    s3 = fmaf(g, mvA[3][r], s3);
                }
                s0 += __shfl_xor(s0, 16); s0 += __shfl_xor(s0, 32);
                s1 += __shfl_xor(s1, 16); s1 += __shfl_xor(s1, 32);
                s2 += __shfl_xor(s2, 16); s2 += __shfl_xor(s2, 32);
                s3 += __shfl_xor(s3, 16); s3 += __shfl_xor(s3, 32);
                int d = __shfl(didx, hi);
                float v = (quad == 0) ? s0 : (quad == 1) ? s1 : (quad == 2) ? s2 : s3;
                unsafeAtomicAdd(&msum[(unsigned int)d * 64u + (unsigned int)quad * 16u + l15], v);
                lo = hi + 1;
                mA &= mA - 1;
            }
            lo = 0;
            while (mB) {
                int hi = __ffs(mB) - 1;
                float s0 = 0.f, s1 = 0.f, s2 = 0.f, s3 = 0.f;
                #pragma unroll
                for (int r = 0; r < 4; ++r) {
                    int gr = rowb + r;
                    float g = (gr >= lo && gr <= hi) ? gB[r] : 0.f;
                    s0 = fmaf(g, mvB[0][r], s0);
                    s1 = fmaf(g, mvB[1][r], s1);
                    s2 = fmaf(g, mvB[2][r], s2);
                    s3 = fmaf(g, mvB[3][r], s3);
                }
                s0 += __shfl_xor(s0, 16); s0 += __shfl_xor(s0, 32);
                s1 += __shfl_xor(s1, 16); s1 += __shfl_xor(s1, 32);
                s2 += __shfl_xor(s2, 16); s2 += __shfl_xor(s2, 32);
                s3 += __shfl_xor(s3, 16); s3 += __shfl_xor(s3, 32);
                int d = __shfl(didx, 16 + hi);
                float v = (quad == 0) ? s0 : (quad == 1) ? s1 : (quad == 2) ? s2 : s3;
                unsafeAtomicAdd(&msum[(unsigned int)d * 64u + (unsigned int)quad * 16u + l15], v);
                lo = hi + 1;
                mB &= mB - 1;
            }
        }
    } else {
        // ---------------- fallback path (no workspace) ----------------
        const int isb = detect_is_bf16((const unsigned short*)feat);
        #pragma unroll
        for (int c = 0; c < 4; ++c)
            #pragma unroll
            for (int nt = 0; nt < 4; ++nt) {
                short8 b;
                #pragma unroll
                for (int j = 0; j < 8; ++j)
                    b[j] = (short)f2bf(getf(W1, (c * 32 + quad * 8 + j) * 64 + nt * 16 + l15, isb));
                bw1[c][nt] = b;
            }
        #pragma unroll
        for (int c = 0; c < 2; ++c)
            #pragma unroll
            for (int nt = 0; nt < 4; ++nt) {
                short8 b;
                #pragma unroll
                for (int j = 0; j < 8; ++j)
                    b[j] = (short)f2bf(getf(W2, (c * 32 + quad * 8 + j) * 64 + nt * 16 + l15, isb));
                bw2[c][nt] = b;
            }
        #pragma unroll
        for (int nt = 0; nt < 4; ++nt) {
            int n = nt * 16 + l15;
            b1r[nt]  = getf(b1, n, isb);
            w1lr[nt] = getf(W1, 128 * 64 + n, isb);
            b2r[nt]  = getf(b2, n, isb);
            wer[nt]  = getf(we, n, isb);
        }
        ber = getf(be, 0, isb);

        const int ntiles = N_EDGES / 128;
        for (int t = blockIdx.x; t < ntiles; t += gridDim.x) {
            const int ebase = t * 128 + wave * 16;
            int sidx = 0, didx = 0;
            float sqd = 0.f;
            if (lane < 16) {
                int e = ebase + lane;
                sidx = src[e];
                didx = dst[e];
                float dx = getf(xpos, sidx * 3 + 0, isb) - getf(xpos, didx * 3 + 0, isb);
                float dy = getf(xpos, sidx * 3 + 1, isb) - getf(xpos, didx * 3 + 1, isb);
                float dz = getf(xpos, sidx * 3 + 2, isb) - getf(xpos, didx * 3 + 2, isb);
                sqd = dx * dx + dy * dy + dz * dz;
            }
            const int sn     = __shfl(sidx, l15);
            const int dn_row = __shfl(didx, l15);

            floatx4 acc[4];
            #pragma unroll
            for (int nt = 0; nt < 4; ++nt) acc[nt] = (floatx4){0.f, 0.f, 0.f, 0.f};
            #pragma unroll
            for (int c = 0; c < 4; ++c) {
                const int node = (c < 2) ? sn : dn_row;
                const unsigned int aoff = (unsigned int)node * 64u + (c & 1) * 32 + quad * 8;
                short8 a = get8bf(feat, aoff, isb);
                #pragma unroll
                for (int nt = 0; nt < 4; ++nt)
                    acc[nt] = __builtin_amdgcn_mfma_f32_16x16x32_bf16(a, bw1[c][nt], acc[nt], 0, 0, 0);
            }

            float sq[4];
            #pragma unroll
            for (int r = 0; r < 4; ++r) sq[r] = __shfl(sqd, rowb + r);
            #pragma unroll
            for (int nt = 0; nt < 4; ++nt)
                #pragma unroll
                for (int r = 0; r < 4; ++r) {
                    float v = fmaxf(acc[nt][r] + b1r[nt] + sq[r] * w1lr[nt], 0.f);
                    sA2[wave][rowb + r][nt * 16 + l15] = (short)f2bf(v);
                }
            COMPILER_FENCE();
            WAIT_LDS();

            floatx4 acc2[4];
            #pragma unroll
            for (int nt = 0; nt < 4; ++nt) acc2[nt] = (floatx4){0.f, 0.f, 0.f, 0.f};
            #pragma unroll
            for (int c = 0; c < 2; ++c) {
                short8 a = *reinterpret_cast<const short8*>(&sA2[wave][l15][c * 32 + quad * 8]);
                #pragma unroll
                for (int nt = 0; nt < 4; ++nt)
                    acc2[nt] = __builtin_amdgcn_mfma_f32_16x16x32_bf16(a, bw2[c][nt], acc2[nt], 0, 0, 0);
            }
            COMPILER_FENCE();
            WAIT_LDS();

            float mval[4][4];
            float part[4] = {0.f, 0.f, 0.f, 0.f};
            #pragma unroll
            for (int nt = 0; nt < 4; ++nt)
                #pragma unroll
                for (int r = 0; r < 4; ++r) {
                    float v = fmaxf(acc2[nt][r] + b2r[nt], 0.f);
                    mval[nt][r] = v;
                    part[r] += v * wer[nt];
                }
            #pragma unroll
            for (int off = 1; off < 16; off <<= 1)
                #pragma unroll
                for (int r = 0; r < 4; ++r) part[r] += __shfl_xor(part[r], off);
            float gate[4];
            #pragma unroll
            for (int r = 0; r < 4; ++r)
                gate[r] = 1.f / (1.f + __expf(-(part[r] + ber)));

            #pragma unroll
            for (int r = 0; r < 4; ++r) {
                int dn = __shfl(didx, rowb + r);
                unsigned int base = (unsigned int)dn * 64u;
                if (base + 64u <= msum_cap) {
                    #pragma unroll
                    for (int nt = 0; nt < 4; ++nt)
                        unsafeAtomicAdd(&msum[base + nt * 16 + l15], mval[nt][r] * gate[r]);
                }
            }
        }
    }
}

// ---------------------------------------------------------------------------
// Node kernel: per wave a 16-node MFMA M-tile; reads f32 msum directly.
// ---------------------------------------------------------------------------
__global__ __launch_bounds__(256, 2) void node_kernel(
    const float* __restrict__ msum,
    const unsigned short* __restrict__ u1t, const unsigned short* __restrict__ u2t,
    const void* __restrict__ feat,
    const void* __restrict__ U1, const void* __restrict__ c1v,
    const void* __restrict__ U2, const void* __restrict__ c2v,
    void* __restrict__ out)
{
    __shared__ __align__(16) short sT[4][16][72];
    __shared__ __align__(16) float sF[4][16][68];

    const int isb  = detect_is_bf16((const unsigned short*)feat);
    const int tid  = threadIdx.x;
    const int wave = tid >> 6;
    const int lane = tid & 63;
    const int l15  = lane & 15;
    const int quad = lane >> 4;

    short8 u1f[2][4], u2f[2][4];
    if (u1t) {
        #pragma unroll
        for (int nt = 0; nt < 4; ++nt) {
            const int n = nt * 16 + l15;
            #pragma unroll
            for (int c = 0; c < 2; ++c) {
                u1f[c][nt] = *reinterpret_cast<const short8*>(u1t + n * 64 + c * 32 + quad * 8);
                u2f[c][nt] = *reinterpret_cast<const short8*>(u2t + n * 64 + c * 32 + quad * 8);
            }
        }
    } else {
        #pragma unroll
        for (int c = 0; c < 2; ++c)
            #pragma unroll
            for (int nt = 0; nt < 4; ++nt) {
                short8 a, b;
                #pragma unroll
                for (int j = 0; j < 8; ++j) {
                    int k = c * 32 + quad * 8 + j, n = nt * 16 + l15;
                    a[j] = (short)f2bf(getf(U1, k * 64 + n, isb));
                    b[j] = (short)f2bf(getf(U2, k * 64 + n, isb));
                }
                u1f[c][nt] = a; u2f[c][nt] = b;
            }
    }
    float c1r[4], c2r[4];
    #pragma unroll
    for (int nt = 0; nt < 4; ++nt) {
        c1r[nt] = getf(c1v, nt * 16 + l15, isb);
        c2r[nt] = getf(c2v, nt * 16 + l15, isb);
    }
    const int rowb = quad * 4;

    const int ntile = (N_NODES + 15) / 16;   // 3125
    const int t = blockIdx.x * 4 + wave;
    if (t < ntile) {
        const int node = t * 16 + l15;

        // ---- message sum (f32 msum) + h fragments ----
        short8 ah[2];
        #pragma unroll
        for (int c = 0; c < 2; ++c) {
            unsigned int off = (unsigned int)node * 64u + c * 32 + quad * 8;
            float4 m0 = *reinterpret_cast<const float4*>(msum + off);
            float4 m1 = *reinterpret_cast<const float4*>(msum + off + 4);
            float mv[8] = {m0.x, m0.y, m0.z, m0.w, m1.x, m1.y, m1.z, m1.w};
            float hv[8];
            if (isb) {
                short8 fv = *reinterpret_cast<const short8*>((const short*)feat + off);
                #pragma unroll
                for (int j = 0; j < 8; ++j) hv[j] = bf2f((unsigned short)fv[j]);
            } else {
                float4 f0 = *reinterpret_cast<const float4*>((const float*)feat + off);
                float4 f1 = *reinterpret_cast<const float4*>((const float*)feat + off + 4);
                hv[0] = f0.x; hv[1] = f0.y; hv[2] = f0.z; hv[3] = f0.w;
                hv[4] = f1.x; hv[5] = f1.y; hv[6] = f1.z; hv[7] = f1.w;
            }
            short8 a;
            #pragma unroll
            for (int j = 0; j < 8; ++j) a[j] = (short)f2bf(mv[j] + hv[j]);
            ah[c] = a;
        }

        // ---- layer 1: relu(h@U1+c1) ----
        floatx4 acc[4];
        #pragma unroll
        for (int nt = 0; nt < 4; ++nt) acc[nt] = (floatx4){0.f, 0.f, 0.f, 0.f};
        #pragma unroll
        for (int c = 0; c < 2; ++c)
            #pragma unroll
            for (int nt = 0; nt < 4; ++nt)
                acc[nt] = __builtin_amdgcn_mfma_f32_16x16x32_bf16(ah[c], u1f[c][nt], acc[nt], 0, 0, 0);

        #pragma unroll
        for (int nt = 0; nt < 4; ++nt)
            #pragma unroll
            for (int r = 0; r < 4; ++r) {
                float v = fmaxf(acc[nt][r] + c1r[nt], 0.f);
                sT[wave][rowb + r][nt * 16 + l15] = (short)f2bf(v);
            }
        COMPILER_FENCE();
        WAIT_LDS();

        // ---- layer 2 ----
        floatx4 acc2[4];
        #pragma unroll
        for (int nt = 0; nt < 4; ++nt) acc2[nt] = (floatx4){0.f, 0.f, 0.f, 0.f};
        #pragma unroll
        for (int c = 0; c < 2; ++c) {
            short8 a = *reinterpret_cast<const short8*>(&sT[wave][l15][c * 32 + quad * 8]);
            #pragma unroll
            for (int nt = 0; nt < 4; ++nt)
                acc2[nt] = __builtin_amdgcn_mfma_f32_16x16x32_bf16(a, u2f[c][nt], acc2[nt], 0, 0, 0);
        }
        COMPILER_FENCE();

        // ---- epilogue: D-layout -> f32 LDS -> row-coalesced (+feat) store ----
        #pragma unroll
        for (int nt = 0; nt < 4; ++nt)
            #pragma unroll
            for (int r = 0; r < 4; ++r)
                sF[wave][rowb + r][nt * 16 + l15] = acc2[nt][r] + c2r[nt];
        COMPILER_FENCE();
        WAIT_LDS();

        const unsigned int ob = (unsigned int)node * 64u + quad * 16;
        if (isb) {
            const unsigned short* fp = (const unsigned short*)feat + ob;
            unsigned short* op = (unsigned short*)out + ob;
            #pragma unroll
            for (int k = 0; k < 2; ++k) {
                ushort4 o0, o1;
                float4 v0 = *reinterpret_cast<const float4*>(&sF[wave][l15][quad * 16 + k * 8]);
                float4 v1 = *reinterpret_cast<const float4*>(&sF[wave][l15][quad * 16 + k * 8 + 4]);
                const ushort4 f0 = *reinterpret_cast<const ushort4*>(fp + k * 8);
                const ushort4 f1 = *reinterpret_cast<const ushort4*>(fp + k * 8 + 4);
                o0.x = f2bf(v0.x + bf2f(f0.x)); o0.y = f2bf(v0.y + bf2f(f0.y));
                o0.z = f2bf(v0.z + bf2f(f0.z)); o0.w = f2bf(v0.w + bf2f(f0.w));
                o1.x = f2bf(v1.x + bf2f(f1.x)); o1.y = f2bf(v1.y + bf2f(f1.y));
                o1.z = f2bf(v1.z + bf2f(f1.z)); o1.w = f2bf(v1.w + bf2f(f1.w));
                *reinterpret_cast<ushort4*>(op + k * 8)     = o0;
                *reinterpret_cast<ushort4*>(op + k * 8 + 4) = o1;
            }
        } else {
            const float* fp = (const float*)feat + ob;
            float* op = (float*)out + ob;
            #pragma unroll
            for (int k = 0; k < 4; ++k) {
                float4 v = *reinterpret_cast<const float4*>(&sF[wave][l15][quad * 16 + k * 4]);
                float4 f = *reinterpret_cast<const float4*>(fp + k * 4);
                float4 o = {v.x + f.x, v.y + f.y, v.z + f.z, v.w + f.w};
                *reinterpret_cast<float4*>(op + k * 4) = o;
            }
        }
        COMPILER_FENCE();
    }
}

extern "C" void kernel_launch(void* const* d_in, const int* in_sizes, int n_in,
                              void* d_out, int out_size, void* d_ws, size_t ws_size,
                              hipStream_t stream) {
    const void* feat = d_in[0];
    const void* x    = d_in[1];
    const int* src   = (const int*)d_in[2];
    const int* dst   = (const int*)d_in[3];
    const void* W1   = d_in[4];
    const void* b1   = d_in[5];
    const void* W2   = d_in[6];
    const void* b2   = d_in[7];
    const void* we   = d_in[8];
    const void* be   = d_in[9];
    const void* U1   = d_in[10];
    const void* c1   = d_in[11];
    const void* U2   = d_in[12];
    const void* c2   = d_in[13];
    char* ws = (char*)d_ws;

    if (ws_size >= WS_NEED) {
        float* msum = (float*)(ws + MSUM_OFF);
        uint4* epack = (uint4*)(ws + EP_OFF);
        int* deg  = (int*)(ws + DEG_OFF);
        int* offs = (int*)(ws + OFFS_OFF);
        int* pos  = (int*)(ws + POS_OFF);
        unsigned short* fb  = (unsigned short*)(ws + FB_OFF);
        unsigned short* w1t = (unsigned short*)(ws + W1T_OFF);
        unsigned short* w2t = (unsigned short*)(ws + W2T_OFF);
        unsigned short* u1t = (unsigned short*)(ws + U1T_OFF);
        unsigned short* u2t = (unsigned short*)(ws + U2T_OFF);
        float* cst = (float*)(ws + CST_OFF);

        hipMemsetAsync(deg, 0, 204800, stream);
        prep_kernel<<<CVT_BLOCKS + PREPW_BLOCKS + MZ_BLOCKS + HIST_BLOCKS, 256, 0, stream>>>(
            feat, fb, W1, W2, U1, U2, b1, b2, we, be,
            w1t, w2t, u1t, u2t, cst, dst, deg, (uint4*)msum);
        scan1_kernel<<<49, 1024, 0, stream>>>(deg, offs + 51200 - 64);
        scan2_kernel<<<1, 64, 0, stream>>>(offs + 51200 - 64, 49);
        scan3_kernel<<<49, 1024, 0, stream>>>(deg, offs + 51200 - 64, offs, pos);
        permute_kernel<<<(N_EDGES + 255) / 256, 256, 0, stream>>>(feat, x, src, dst, pos, epack);
        edge_kernel<true><<<768, 512, 0, stream>>>(fb, w1t, w2t, cst, feat, x, src, dst, epack,
                                                   W1, b1, W2, b2, we, be,
                                                   msum, (unsigned int)(N_NODES * HDIM));
        node_kernel<<<((N_NODES + 15) / 16 + 3) / 4, 256, 0, stream>>>(
            msum, u1t, u2t, feat, U1, c1, U2, c2, d_out);
    } else {
        float* msum = (float*)ws;
        size_t need = (size_t)N_NODES * HDIM * sizeof(float);
        size_t clr  = need < ws_size ? need : ws_size;
        unsigned int cap = (unsigned int)(ws_size / sizeof(float));
        if (cap > (unsigned int)(N_NODES * HDIM)) cap = (unsigned int)(N_NODES * HDIM);

        hipMemsetAsync(msum, 0, clr, stream);
        edge_kernel<false><<<1250, 512, 0, stream>>>(nullptr, nullptr, nullptr, nullptr,
                                                     feat, x, src, dst,
                                                     nullptr, W1, b1, W2, b2, we, be,
                                                     msum, cap);
        node_kernel<<<((N_NODES + 15) / 16 + 3) / 4, 256, 0, stream>>>(
            msum, nullptr, nullptr, feat, U1, c1, U2, c2, d_out);
    }
}

// Round 8
// 257.353 us; speedup vs baseline: 1.1501x; 1.0446x over previous
//
#include <hip/hip_runtime.h>
#include <hip/hip_bf16.h>
#include <stdint.h>

#define N_NODES 50000
#define N_EDGES 800000
#define HDIM 64
#define SCAN_N (N_NODES + 1)

// ---- workspace layout (CSR path) ----
// msum and deg are adjacent so ONE hipMemsetAsync zeroes both.
#define MSUM_OFF   0                                  // 12,800,000 B f32
#define DEG_OFF    12800000                           // 204,800 B
#define ZERO_BYTES (DEG_OFF + 204800)                 // 13,004,800 one memset
#define PART_OFF   (DEG_OFF + 204800)                 // 49 ints (scan partials)
#define OFFS_OFF   (PART_OFF + 1024)
#define POS_OFF    (OFFS_OFF + 204800)
#define EP_OFF     (POS_OFF + 204800)                 // 16B-aligned
#define FB_OFF     (EP_OFF + 12800000)
#define W1T_OFF    (FB_OFF + (size_t)N_NODES * HDIM * 2)
#define W2T_OFF    (W1T_OFF + 16384)
#define U1T_OFF    (W2T_OFF + 8192)
#define U2T_OFF    (U1T_OFF + 8192)
#define CST_OFF    (U2T_OFF + 8192)
#define WS_NEED    (CST_OFF + 4096)

// fused prep kernel block ranges (no msum-zero phase: memset covers it)
#define CVT_BLOCKS   1563             // ceil(3.2M/8/256) feat->bf16
#define PREPW_BLOCKS 82               // transposed weights + consts
#define HIST_BLOCKS  1024             // dst histogram

typedef __attribute__((ext_vector_type(8))) short short8;
typedef __attribute__((ext_vector_type(4))) float floatx4;

__device__ __forceinline__ float bf2f(unsigned short u) {
    union { unsigned int i; float f; } v; v.i = ((unsigned int)u) << 16; return v.f;
}
__device__ __forceinline__ unsigned short f2bf(float f) {
    __hip_bfloat16 h = __float2bfloat16(f);
    return *reinterpret_cast<unsigned short*>(&h);
}

__device__ __forceinline__ int detect_is_bf16(const unsigned short* p) {
    int cnt = 0;
    #pragma unroll
    for (int i = 0; i < 64; ++i) {
        unsigned short b = p[i];
        int e = (b >> 7) & 0xFF;
        cnt += ((e >= 97 && e <= 157) || (b & 0x7FFF) == 0) ? 1 : 0;
    }
    return cnt >= 56;
}

__device__ __forceinline__ float getf(const void* p, unsigned int i, int isb) {
    return isb ? bf2f(((const unsigned short*)p)[i]) : ((const float*)p)[i];
}

__device__ __forceinline__ short8 get8bf(const void* p, unsigned int i, int isb) {
    if (isb) {
        return *reinterpret_cast<const short8*>((const short*)p + i);
    } else {
        const float4 f0 = *reinterpret_cast<const float4*>((const float*)p + i);
        const float4 f1 = *reinterpret_cast<const float4*>((const float*)p + i + 4);
        short8 a;
        a[0] = (short)f2bf(f0.x); a[1] = (short)f2bf(f0.y);
        a[2] = (short)f2bf(f0.z); a[3] = (short)f2bf(f0.w);
        a[4] = (short)f2bf(f1.x); a[5] = (short)f2bf(f1.y);
        a[6] = (short)f2bf(f1.z); a[7] = (short)f2bf(f1.w);
        return a;
    }
}

#define COMPILER_FENCE() asm volatile("" ::: "memory")
#define WAIT_LDS() __builtin_amdgcn_s_waitcnt(0xC07F)   // lgkmcnt(0) only

// ---------------------------------------------------------------------------
// Fused prep: feat->bf16 | transposed weights + f32 consts | dst histogram
// ---------------------------------------------------------------------------
__global__ __launch_bounds__(256) void prep_kernel(
    const void* __restrict__ feat, unsigned short* __restrict__ fb,
    const void* __restrict__ W1, const void* __restrict__ W2,
    const void* __restrict__ U1, const void* __restrict__ U2,
    const void* __restrict__ b1, const void* __restrict__ b2,
    const void* __restrict__ we, const void* __restrict__ be,
    unsigned short* __restrict__ w1t, unsigned short* __restrict__ w2t,
    unsigned short* __restrict__ u1t, unsigned short* __restrict__ u2t,
    float* __restrict__ cst,
    const int* __restrict__ dst, int* __restrict__ deg)
{
    const int b = blockIdx.x;
    if (b < CVT_BLOCKS) {
        const int isb = detect_is_bf16((const unsigned short*)feat);
        int i = (b * 256 + threadIdx.x) * 8;
        if (i >= N_NODES * HDIM) return;
        if (isb) {
            *reinterpret_cast<uint4*>(fb + i) =
                *reinterpret_cast<const uint4*>((const unsigned short*)feat + i);
        } else {
            float4 f0 = *reinterpret_cast<const float4*>((const float*)feat + i);
            float4 f1 = *reinterpret_cast<const float4*>((const float*)feat + i + 4);
            ushort4 a = {f2bf(f0.x), f2bf(f0.y), f2bf(f0.z), f2bf(f0.w)};
            ushort4 c = {f2bf(f1.x), f2bf(f1.y), f2bf(f1.z), f2bf(f1.w)};
            *reinterpret_cast<ushort4*>(fb + i)     = a;
            *reinterpret_cast<ushort4*>(fb + i + 4) = c;
        }
    } else if (b < CVT_BLOCKS + PREPW_BLOCKS) {
        const int isb = detect_is_bf16((const unsigned short*)feat);
        int idx = (b - CVT_BLOCKS) * 256 + threadIdx.x;
        if (idx < 8192) {                               // W1T [64][128]
            int n = idx >> 7, k = idx & 127;
            w1t[idx] = f2bf(getf(W1, k * 64 + n, isb));
        } else if (idx < 12288) {                       // W2T [64][64]
            int i = idx - 8192, n = i >> 6, k = i & 63;
            w2t[i] = f2bf(getf(W2, k * 64 + n, isb));
        } else if (idx < 16384) {                       // U1T
            int i = idx - 12288, n = i >> 6, k = i & 63;
            u1t[i] = f2bf(getf(U1, k * 64 + n, isb));
        } else if (idx < 20480) {                       // U2T
            int i = idx - 16384, n = i >> 6, k = i & 63;
            u2t[i] = f2bf(getf(U2, k * 64 + n, isb));
        } else if (idx < 20737) {                       // f32 consts table
            int i = idx - 20480;
            float v;
            if (i < 64)       v = getf(b1, i, isb);
            else if (i < 128) v = getf(W1, 128 * 64 + (i - 64), isb);   // sqd row
            else if (i < 192) v = getf(b2, i - 128, isb);
            else if (i < 256) v = getf(we, i - 192, isb);
            else              v = getf(be, 0, isb);
            cst[i] = v;
        }
    } else {
        int e0 = (b - CVT_BLOCKS - PREPW_BLOCKS) * 256 + threadIdx.x;
        for (int e = e0; e < N_EDGES; e += HIST_BLOCKS * 256)
            atomicAdd(&deg[dst[e]], 1);
    }
}

// ---------------------------------------------------------------------------
// Scan, 2 launches: scan1 (block partials), scan3 (inline 49-partial prefix
// via wave shuffle reduce — replaces the serial scan2 kernel).
// ---------------------------------------------------------------------------
__global__ void scan1_kernel(const int* __restrict__ deg, int* __restrict__ part) {
    __shared__ int s[1024];
    int g = blockIdx.x * 1024 + threadIdx.x;
    s[threadIdx.x] = (g < SCAN_N) ? deg[g] : 0;
    __syncthreads();
    for (int off = 512; off > 0; off >>= 1) {
        if (threadIdx.x < off) s[threadIdx.x] += s[threadIdx.x + off];
        __syncthreads();
    }
    if (threadIdx.x == 0) part[blockIdx.x] = s[0];
}

__global__ void scan3_kernel(const int* __restrict__ deg, const int* __restrict__ part,
                             int* __restrict__ offs, int* __restrict__ pos) {
    __shared__ int s[1024];
    __shared__ int sbase;
    // exclusive prefix of the 49 block partials, wave-parallel
    if (threadIdx.x < 64) {
        int v = (threadIdx.x < blockIdx.x) ? part[threadIdx.x] : 0;
        #pragma unroll
        for (int off = 32; off >= 1; off >>= 1) v += __shfl_xor(v, off);
        if (threadIdx.x == 0) sbase = v;
    }
    int g = blockIdx.x * 1024 + threadIdx.x;
    int v = (g < SCAN_N) ? deg[g] : 0;
    s[threadIdx.x] = v;
    __syncthreads();
    for (int off = 1; off < 1024; off <<= 1) {
        int t = (threadIdx.x >= off) ? s[threadIdx.x - off] : 0;
        __syncthreads();
        s[threadIdx.x] += t;
        __syncthreads();
    }
    int excl = s[threadIdx.x] - v + sbase;
    if (g < SCAN_N) { offs[g] = excl; pos[g] = excl; }
}

// ---------------------------------------------------------------------------
// Permute: counting-sort edges by dst; pack {src, dst, sqd} per slot.
// ---------------------------------------------------------------------------
__global__ __launch_bounds__(256) void permute_kernel(
    const void* __restrict__ feat, const void* __restrict__ xpos,
    const int* __restrict__ src, const int* __restrict__ dst,
    int* __restrict__ pos, uint4* __restrict__ epack)
{
    const int isb = detect_is_bf16((const unsigned short*)feat);
    int e = blockIdx.x * 256 + threadIdx.x;
    if (e < N_EDGES) {
        int s = src[e], d = dst[e];
        int slot = atomicAdd(&pos[d], 1);
        float dx = getf(xpos, s * 3 + 0, isb) - getf(xpos, d * 3 + 0, isb);
        float dy = getf(xpos, s * 3 + 1, isb) - getf(xpos, d * 3 + 1, isb);
        float dz = getf(xpos, s * 3 + 2, isb) - getf(xpos, d * 3 + 2, isb);
        float sqd = dx * dx + dy * dy + dz * dz;
        uint4 p;
        p.x = (unsigned int)s;
        p.y = (unsigned int)d;
        p.z = __float_as_uint(sqd);
        p.w = 0u;
        epack[slot] = p;
    }
}

// ---------------------------------------------------------------------------
// Edge kernel: r5-proven config (dual-tile ILP, dual sA2 buffers, (512,4),
// LDS 61440, VGPR 60 no-spill) + CHUNKED contiguous tile ranges per block
// for dst-gather/atomic L2 locality (dst-sorted edges => each block touches
// a ~17KB msum/fbf window).
// ---------------------------------------------------------------------------
template <bool CSR>
__global__ __launch_bounds__(512, 4) void edge_kernel(
    const unsigned short* __restrict__ fbf,
    const unsigned short* __restrict__ w1t, const unsigned short* __restrict__ w2t,
    const float* __restrict__ cst,
    const void* __restrict__ feat, const void* __restrict__ xpos,
    const int* __restrict__ src, const int* __restrict__ dst,
    const uint4* __restrict__ epack,
    const void* __restrict__ W1, const void* __restrict__ b1,
    const void* __restrict__ W2, const void* __restrict__ b2,
    const void* __restrict__ we, const void* __restrict__ be,
    float* __restrict__ msum, unsigned int msum_cap)
{
    __shared__ __align__(16) short sW1[16][64][8];   // frag f=c*4+nt, lane, 16B
    __shared__ __align__(16) short sW2[8][64][8];
    __shared__ __align__(16) short sA2[2][8][16][72];

    const int tid  = threadIdx.x;
    const int wave = tid >> 6;
    const int lane = tid & 63;
    const int l15  = lane & 15;
    const int quad = lane >> 4;
    const int rowb = quad * 4;

    float b1r[4], w1lr[4], b2r[4], wer[4];
    float ber;
    short8 bw1[4][4];    // fallback-only
    short8 bw2[2][4];

    if constexpr (CSR) {
        for (int i = tid; i < 16 * 64; i += 512) {
            int f = i >> 6, l = i & 63;
            int n = (f & 3) * 16 + (l & 15);
            int k0 = (f >> 2) * 32 + (l >> 4) * 8;
            *reinterpret_cast<short8*>(&sW1[f][l][0]) =
                *reinterpret_cast<const short8*>(w1t + n * 128 + k0);
        }
        for (int i = tid; i < 8 * 64; i += 512) {
            int f = i >> 6, l = i & 63;
            int n = (f & 3) * 16 + (l & 15);
            int k0 = (f >> 2) * 32 + (l >> 4) * 8;
            *reinterpret_cast<short8*>(&sW2[f][l][0]) =
                *reinterpret_cast<const short8*>(w2t + n * 64 + k0);
        }
        #pragma unroll
        for (int nt = 0; nt < 4; ++nt) {
            int n = nt * 16 + l15;
            b1r[nt]  = cst[n];
            w1lr[nt] = cst[64 + n];
            b2r[nt]  = cst[128 + n];
            wer[nt]  = cst[192 + n];
        }
        ber = cst[256];
        __syncthreads();

        const int nbiter = N_EDGES / 256;    // 3125
        const int per = (nbiter + (int)gridDim.x - 1) / (int)gridDim.x;   // 5 @ grid 625
        const int t0 = blockIdx.x * per;
        const int t1 = (t0 + per < nbiter) ? t0 + per : nbiter;
        for (int it = t0; it < t1; ++it) {
            const int ebase = it * 256 + wave * 16;

            int sidx = 0, didx = 0;
            float sqd = 0.f;
            if (lane < 32) {
                int e = ebase + l15 + ((lane >> 4) << 7);   // lanes 16-31: +128
                uint4 p = epack[e];
                sidx = (int)p.x;
                didx = (int)p.y;
                sqd  = __uint_as_float(p.z);
            }
            const int snA = __shfl(sidx, l15);
            const int dnA = __shfl(didx, l15);
            const int snB = __shfl(sidx, l15 + 16);
            const int dnB = __shfl(didx, l15 + 16);

            // ---- gathers for both tiles (8 independent loads in flight) ----
            short8 caA[4], caB[4];
            #pragma unroll
            for (int c = 0; c < 4; ++c) {
                const int nA = (c < 2) ? snA : dnA;
                const int nB = (c < 2) ? snB : dnB;
                caA[c] = *reinterpret_cast<const short8*>(
                    (const short*)fbf + (unsigned int)nA * 64u + (c & 1) * 32 + quad * 8);
                caB[c] = *reinterpret_cast<const short8*>(
                    (const short*)fbf + (unsigned int)nB * 64u + (c & 1) * 32 + quad * 8);
            }

            // ---- layer 1 (both tiles, shared B frags) ----
            floatx4 accA[4], accB[4];
            #pragma unroll
            for (int nt = 0; nt < 4; ++nt) {
                accA[nt] = (floatx4){0.f, 0.f, 0.f, 0.f};
                accB[nt] = (floatx4){0.f, 0.f, 0.f, 0.f};
            }
            #pragma unroll
            for (int c = 0; c < 4; ++c) {
                #pragma unroll
                for (int nt = 0; nt < 4; ++nt) {
                    short8 wb = *reinterpret_cast<const short8*>(&sW1[c * 4 + nt][lane][0]);
                    accA[nt] = __builtin_amdgcn_mfma_f32_16x16x32_bf16(caA[c], wb, accA[nt], 0, 0, 0);
                    accB[nt] = __builtin_amdgcn_mfma_f32_16x16x32_bf16(caB[c], wb, accB[nt], 0, 0, 0);
                }
            }

            // ---- epilogue 1 -> LDS (both tiles) ----
            float sqA[4], sqB[4];
            #pragma unroll
            for (int r = 0; r < 4; ++r) {
                sqA[r] = __shfl(sqd, rowb + r);
                sqB[r] = __shfl(sqd, 16 + rowb + r);
            }
            #pragma unroll
            for (int nt = 0; nt < 4; ++nt)
                #pragma unroll
                for (int r = 0; r < 4; ++r) {
                    float vA = fmaxf(fmaf(sqA[r], w1lr[nt], accA[nt][r]) + b1r[nt], 0.f);
                    float vB = fmaxf(fmaf(sqB[r], w1lr[nt], accB[nt][r]) + b1r[nt], 0.f);
                    sA2[0][wave][rowb + r][nt * 16 + l15] = (short)f2bf(vA);
                    sA2[1][wave][rowb + r][nt * 16 + l15] = (short)f2bf(vB);
                }
            COMPILER_FENCE();
            WAIT_LDS();

            // ---- layer 2 (both tiles, shared B frags) ----
            floatx4 acc2A[4], acc2B[4];
            #pragma unroll
            for (int nt = 0; nt < 4; ++nt) {
                acc2A[nt] = (floatx4){0.f, 0.f, 0.f, 0.f};
                acc2B[nt] = (floatx4){0.f, 0.f, 0.f, 0.f};
            }
            #pragma unroll
            for (int c = 0; c < 2; ++c) {
                short8 aA = *reinterpret_cast<const short8*>(&sA2[0][wave][l15][c * 32 + quad * 8]);
                short8 aB = *reinterpret_cast<const short8*>(&sA2[1][wave][l15][c * 32 + quad * 8]);
                #pragma unroll
                for (int nt = 0; nt < 4; ++nt) {
                    short8 wb = *reinterpret_cast<const short8*>(&sW2[c * 4 + nt][lane][0]);
                    acc2A[nt] = __builtin_amdgcn_mfma_f32_16x16x32_bf16(aA, wb, acc2A[nt], 0, 0, 0);
                    acc2B[nt] = __builtin_amdgcn_mfma_f32_16x16x32_bf16(aB, wb, acc2B[nt], 0, 0, 0);
                }
            }
            COMPILER_FENCE();

            // ---- epilogue 2: relu, gate (both tiles) ----
            float mvA[4][4], mvB[4][4];
            float pA[4] = {0.f, 0.f, 0.f, 0.f};
            float pB[4] = {0.f, 0.f, 0.f, 0.f};
            #pragma unroll
            for (int nt = 0; nt < 4; ++nt)
                #pragma unroll
                for (int r = 0; r < 4; ++r) {
                    float vA = fmaxf(acc2A[nt][r] + b2r[nt], 0.f);
                    float vB = fmaxf(acc2B[nt][r] + b2r[nt], 0.f);
                    mvA[nt][r] = vA;
                    mvB[nt][r] = vB;
                    pA[r] = fmaf(vA, wer[nt], pA[r]);
                    pB[r] = fmaf(vB, wer[nt], pB[r]);
                }
            #pragma unroll
            for (int off = 1; off < 16; off <<= 1)
                #pragma unroll
                for (int r = 0; r < 4; ++r) {
                    pA[r] += __shfl_xor(pA[r], off);
                    pB[r] += __shfl_xor(pB[r], off);
                }
            float gA[4], gB[4];
            #pragma unroll
            for (int r = 0; r < 4; ++r) {
                gA[r] = 1.f / (1.f + __expf(-(pA[r] + ber)));
                gB[r] = 1.f / (1.f + __expf(-(pB[r] + ber)));
            }

            // ---- in-register segmented reduce (both tiles) ----
            int grp = (lane >> 4) & 1;
            int nd = __shfl(didx, grp * 16 + ((l15 + 1) & 15));
            int flag = (lane < 32) && ((l15 == 15) || (nd != didx));
            unsigned long long bal = __ballot(flag);
            unsigned int mA = (unsigned int)(bal & 0xFFFFull);
            unsigned int mB = (unsigned int)((bal >> 16) & 0xFFFFull);

            int lo = 0;
            while (mA) {
                int hi = __ffs(mA) - 1;
                float s0 = 0.f, s1 = 0.f, s2 = 0.f, s3 = 0.f;
                #pragma unroll
                for (int r = 0; r < 4; ++r) {
                    int gr = rowb + r;
                    float g = (gr >= lo && gr <= hi) ? gA[r] : 0.f;
                    s0 = fmaf(g, mvA[0][r], s0);
                    s1 = fmaf(g, mvA[1][r], s1);
                    s2 = fmaf(g, mvA[2][r], s2);
                    s3 = fmaf(g, mvA[3][r], s3);
                }
                s0 += __shfl_xor(s0, 16); s0 += __shfl_xor(s0, 32);
                s1 += __shfl_xor(s1, 16); s1 += __shfl_xor(s1, 32);
                s2 += __shfl_xor(s2, 16); s2 += __shfl_xor(s2, 32);
                s3 += __shfl_xor(s3, 16); s3 += __shfl_xor(s3, 32);
                int d = __shfl(didx, hi);
                float v = (quad == 0) ? s0 : (quad == 1) ? s1 : (quad == 2) ? s2 : s3;
                unsafeAtomicAdd(&msum[(unsigned int)d * 64u + (unsigned int)quad * 16u + l15], v);
                lo = hi + 1;
                mA &= mA - 1;
            }
            lo = 0;
            while (mB) {
                int hi = __ffs(mB) - 1;
                float s0 = 0.f, s1 = 0.f, s2 = 0.f, s3 = 0.f;
                #pragma unroll
                for (int r = 0; r < 4; ++r) {
                    int gr = rowb + r;
                    float g = (gr >= lo && gr <= hi) ? gB[r] : 0.f;
                    s0 = fmaf(g, mvB[0][r], s0);
                    s1 = fmaf(g, mvB[1][r], s1);
                    s2 = fmaf(g, mvB[2][r], s2);
                    s3 = fmaf(g, mvB[3][r], s3);
                }
                s0 += __shfl_xor(s0, 16); s0 += __shfl_xor(s0, 32);
                s1 += __shfl_xor(s1, 16); s1 += __shfl_xor(s1, 32);
                s2 += __shfl_xor(s2, 16); s2 += __shfl_xor(s2, 32);
                s3 += __shfl_xor(s3, 16); s3 += __shfl_xor(s3, 32);
                int d = __shfl(didx, 16 + hi);
                float v = (quad == 0) ? s0 : (quad == 1) ? s1 : (quad == 2) ? s2 : s3;
                unsafeAtomicAdd(&msum[(unsigned int)d * 64u + (unsigned int)quad * 16u + l15], v);
                lo = hi + 1;
                mB &= mB - 1;
            }
        }
    } else {
        // ---------------- fallback path (no workspace) ----------------
        const int isb = detect_is_bf16((const unsigned short*)feat);
        #pragma unroll
        for (int c = 0; c < 4; ++c)
            #pragma unroll
            for (int nt = 0; nt < 4; ++nt) {
                short8 b;
                #pragma unroll
                for (int j = 0; j < 8; ++j)
                    b[j] = (short)f2bf(getf(W1, (c * 32 + quad * 8 + j) * 64 + nt * 16 + l15, isb));
                bw1[c][nt] = b;
            }
        #pragma unroll
        for (int c = 0; c < 2; ++c)
            #pragma unroll
            for (int nt = 0; nt < 4; ++nt) {
                short8 b;
                #pragma unroll
                for (int j = 0; j < 8; ++j)
                    b[j] = (short)f2bf(getf(W2, (c * 32 + quad * 8 + j) * 64 + nt * 16 + l15, isb));
                bw2[c][nt] = b;
            }
        #pragma unroll
        for (int nt = 0; nt < 4; ++nt) {
            int n = nt * 16 + l15;
            b1r[nt]  = getf(b1, n, isb);
            w1lr[nt] = getf(W1, 128 * 64 + n, isb);
            b2r[nt]  = getf(b2, n, isb);
            wer[nt]  = getf(we, n, isb);
        }
        ber = getf(be, 0, isb);

        const int ntiles = N_EDGES / 128;
        for (int t = blockIdx.x; t < ntiles; t += gridDim.x) {
            const int ebase = t * 128 + wave * 16;
            int sidx = 0, didx = 0;
            float sqd = 0.f;
            if (lane < 16) {
                int e = ebase + lane;
                sidx = src[e];
                didx = dst[e];
                float dx = getf(xpos, sidx * 3 + 0, isb) - getf(xpos, didx * 3 + 0, isb);
                float dy = getf(xpos, sidx * 3 + 1, isb) - getf(xpos, didx * 3 + 1, isb);
                float dz = getf(xpos, sidx * 3 + 2, isb) - getf(xpos, didx * 3 + 2, isb);
                sqd = dx * dx + dy * dy + dz * dz;
            }
            const int sn     = __shfl(sidx, l15);
            const int dn_row = __shfl(didx, l15);

            floatx4 acc[4];
            #pragma unroll
            for (int nt = 0; nt < 4; ++nt) acc[nt] = (floatx4){0.f, 0.f, 0.f, 0.f};
            #pragma unroll
            for (int c = 0; c < 4; ++c) {
                const int node = (c < 2) ? sn : dn_row;
                const unsigned int aoff = (unsigned int)node * 64u + (c & 1) * 32 + quad * 8;
                short8 a = get8bf(feat, aoff, isb);
                #pragma unroll
                for (int nt = 0; nt < 4; ++nt)
                    acc[nt] = __builtin_amdgcn_mfma_f32_16x16x32_bf16(a, bw1[c][nt], acc[nt], 0, 0, 0);
            }

            float sq[4];
            #pragma unroll
            for (int r = 0; r < 4; ++r) sq[r] = __shfl(sqd, rowb + r);
            #pragma unroll
            for (int nt = 0; nt < 4; ++nt)
                #pragma unroll
                for (int r = 0; r < 4; ++r) {
                    float v = fmaxf(acc[nt][r] + b1r[nt] + sq[r] * w1lr[nt], 0.f);
                    sA2[0][wave][rowb + r][nt * 16 + l15] = (short)f2bf(v);
                }
            COMPILER_FENCE();
            WAIT_LDS();

            floatx4 acc2[4];
            #pragma unroll
            for (int nt = 0; nt < 4; ++nt) acc2[nt] = (floatx4){0.f, 0.f, 0.f, 0.f};
            #pragma unroll
            for (int c = 0; c < 2; ++c) {
                short8 a = *reinterpret_cast<const short8*>(&sA2[0][wave][l15][c * 32 + quad * 8]);
                #pragma unroll
                for (int nt = 0; nt < 4; ++nt)
                    acc2[nt] = __builtin_amdgcn_mfma_f32_16x16x32_bf16(a, bw2[c][nt], acc2[nt], 0, 0, 0);
            }
            COMPILER_FENCE();
            WAIT_LDS();

            float mval[4][4];
            float part[4] = {0.f, 0.f, 0.f, 0.f};
            #pragma unroll
            for (int nt = 0; nt < 4; ++nt)
                #pragma unroll
                for (int r = 0; r < 4; ++r) {
                    float v = fmaxf(acc2[nt][r] + b2r[nt], 0.f);
                    mval[nt][r] = v;
                    part[r] += v * wer[nt];
                }
            #pragma unroll
            for (int off = 1; off < 16; off <<= 1)
                #pragma unroll
                for (int r = 0; r < 4; ++r) part[r] += __shfl_xor(part[r], off);
            float gate[4];
            #pragma unroll
            for (int r = 0; r < 4; ++r)
                gate[r] = 1.f / (1.f + __expf(-(part[r] + ber)));

            #pragma unroll
            for (int r = 0; r < 4; ++r) {
                int dn = __shfl(didx, rowb + r);
                unsigned int base = (unsigned int)dn * 64u;
                if (base + 64u <= msum_cap) {
                    #pragma unroll
                    for (int nt = 0; nt < 4; ++nt)
                        unsafeAtomicAdd(&msum[base + nt * 16 + l15], mval[nt][r] * gate[r]);
                }
            }
        }
    }
}

// ---------------------------------------------------------------------------
// Node kernel: per wave a 16-node MFMA M-tile; reads f32 msum directly.
// ---------------------------------------------------------------------------
__global__ __launch_bounds__(256, 2) void node_kernel(
    const float* __restrict__ msum,
    const unsigned short* __restrict__ u1t, const unsigned short* __restrict__ u2t,
    const void* __restrict__ feat,
    const void* __restrict__ U1, const void* __restrict__ c1v,
    const void* __restrict__ U2, const void* __restrict__ c2v,
    void* __restrict__ out)
{
    __shared__ __align__(16) short sT[4][16][72];
    __shared__ __align__(16) float sF[4][16][68];

    const int isb  = detect_is_bf16((const unsigned short*)feat);
    const int tid  = threadIdx.x;
    const int wave = tid >> 6;
    const int lane = tid & 63;
    const int l15  = lane & 15;
    const int quad = lane >> 4;

    short8 u1f[2][4], u2f[2][4];
    if (u1t) {
        #pragma unroll
        for (int nt = 0; nt < 4; ++nt) {
            const int n = nt * 16 + l15;
            #pragma unroll
            for (int c = 0; c < 2; ++c) {
                u1f[c][nt] = *reinterpret_cast<const short8*>(u1t + n * 64 + c * 32 + quad * 8);
                u2f[c][nt] = *reinterpret_cast<const short8*>(u2t + n * 64 + c * 32 + quad * 8);
            }
        }
    } else {
        #pragma unroll
        for (int c = 0; c < 2; ++c)
            #pragma unroll
            for (int nt = 0; nt < 4; ++nt) {
                short8 a, b;
                #pragma unroll
                for (int j = 0; j < 8; ++j) {
                    int k = c * 32 + quad * 8 + j, n = nt * 16 + l15;
                    a[j] = (short)f2bf(getf(U1, k * 64 + n, isb));
                    b[j] = (short)f2bf(getf(U2, k * 64 + n, isb));
                }
                u1f[c][nt] = a; u2f[c][nt] = b;
            }
    }
    float c1r[4], c2r[4];
    #pragma unroll
    for (int nt = 0; nt < 4; ++nt) {
        c1r[nt] = getf(c1v, nt * 16 + l15, isb);
        c2r[nt] = getf(c2v, nt * 16 + l15, isb);
    }
    const int rowb = quad * 4;

    const int ntile = (N_NODES + 15) / 16;   // 3125
    const int t = blockIdx.x * 4 + wave;
    if (t < ntile) {
        const int node = t * 16 + l15;

        // ---- message sum (f32 msum) + h fragments ----
        short8 ah[2];
        #pragma unroll
        for (int c = 0; c < 2; ++c) {
            unsigned int off = (unsigned int)node * 64u + c * 32 + quad * 8;
            float4 m0 = *reinterpret_cast<const float4*>(msum + off);
            float4 m1 = *reinterpret_cast<const float4*>(msum + off + 4);
            float mv[8] = {m0.x, m0.y, m0.z, m0.w, m1.x, m1.y, m1.z, m1.w};
            float hv[8];
            if (isb) {
                short8 fv = *reinterpret_cast<const short8*>((const short*)feat + off);
                #pragma unroll
                for (int j = 0; j < 8; ++j) hv[j] = bf2f((unsigned short)fv[j]);
            } else {
                float4 f0 = *reinterpret_cast<const float4*>((const float*)feat + off);
                float4 f1 = *reinterpret_cast<const float4*>((const float*)feat + off + 4);
                hv[0] = f0.x; hv[1] = f0.y; hv[2] = f0.z; hv[3] = f0.w;
                hv[4] = f1.x; hv[5] = f1.y; hv[6] = f1.z; hv[7] = f1.w;
            }
            short8 a;
            #pragma unroll
            for (int j = 0; j < 8; ++j) a[j] = (short)f2bf(mv[j] + hv[j]);
            ah[c] = a;
        }

        // ---- layer 1: relu(h@U1+c1) ----
        floatx4 acc[4];
        #pragma unroll
        for (int nt = 0; nt < 4; ++nt) acc[nt] = (floatx4){0.f, 0.f, 0.f, 0.f};
        #pragma unroll
        for (int c = 0; c < 2; ++c)
            #pragma unroll
            for (int nt = 0; nt < 4; ++nt)
                acc[nt] = __builtin_amdgcn_mfma_f32_16x16x32_bf16(ah[c], u1f[c][nt], acc[nt], 0, 0, 0);

        #pragma unroll
        for (int nt = 0; nt < 4; ++nt)
            #pragma unroll
            for (int r = 0; r < 4; ++r) {
                float v = fmaxf(acc[nt][r] + c1r[nt], 0.f);
                sT[wave][rowb + r][nt * 16 + l15] = (short)f2bf(v);
            }
        COMPILER_FENCE();
        WAIT_LDS();

        // ---- layer 2 ----
        floatx4 acc2[4];
        #pragma unroll
        for (int nt = 0; nt < 4; ++nt) acc2[nt] = (floatx4){0.f, 0.f, 0.f, 0.f};
        #pragma unroll
        for (int c = 0; c < 2; ++c) {
            short8 a = *reinterpret_cast<const short8*>(&sT[wave][l15][c * 32 + quad * 8]);
            #pragma unroll
            for (int nt = 0; nt < 4; ++nt)
                acc2[nt] = __builtin_amdgcn_mfma_f32_16x16x32_bf16(a, u2f[c][nt], acc2[nt], 0, 0, 0);
        }
        COMPILER_FENCE();

        // ---- epilogue: D-layout -> f32 LDS -> row-coalesced (+feat) store ----
        #pragma unroll
        for (int nt = 0; nt < 4; ++nt)
            #pragma unroll
            for (int r = 0; r < 4; ++r)
                sF[wave][rowb + r][nt * 16 + l15] = acc2[nt][r] + c2r[nt];
        COMPILER_FENCE();
        WAIT_LDS();

        const unsigned int ob = (unsigned int)node * 64u + quad * 16;
        if (isb) {
            const unsigned short* fp = (const unsigned short*)feat + ob;
            unsigned short* op = (unsigned short*)out + ob;
            #pragma unroll
            for (int k = 0; k < 2; ++k) {
                ushort4 o0, o1;
                float4 v0 = *reinterpret_cast<const float4*>(&sF[wave][l15][quad * 16 + k * 8]);
                float4 v1 = *reinterpret_cast<const float4*>(&sF[wave][l15][quad * 16 + k * 8 + 4]);
                const ushort4 f0 = *reinterpret_cast<const ushort4*>(fp + k * 8);
                const ushort4 f1 = *reinterpret_cast<const ushort4*>(fp + k * 8 + 4);
                o0.x = f2bf(v0.x + bf2f(f0.x)); o0.y = f2bf(v0.y + bf2f(f0.y));
                o0.z = f2bf(v0.z + bf2f(f0.z)); o0.w = f2bf(v0.w + bf2f(f0.w));
                o1.x = f2bf(v1.x + bf2f(f1.x)); o1.y = f2bf(v1.y + bf2f(f1.y));
                o1.z = f2bf(v1.z + bf2f(f1.z)); o1.w = f2bf(v1.w + bf2f(f1.w));
                *reinterpret_cast<ushort4*>(op + k * 8)     = o0;
                *reinterpret_cast<ushort4*>(op + k * 8 + 4) = o1;
            }
        } else {
            const float* fp = (const float*)feat + ob;
            float* op = (float*)out + ob;
            #pragma unroll
            for (int k = 0; k < 4; ++k) {
                float4 v = *reinterpret_cast<const float4*>(&sF[wave][l15][quad * 16 + k * 4]);
                float4 f = *reinterpret_cast<const float4*>(fp + k * 4);
                float4 o = {v.x + f.x, v.y + f.y, v.z + f.z, v.w + f.w};
                *reinterpret_cast<float4*>(op + k * 4) = o;
            }
        }
        COMPILER_FENCE();
    }
}

extern "C" void kernel_launch(void* const* d_in, const int* in_sizes, int n_in,
                              void* d_out, int out_size, void* d_ws, size_t ws_size,
                              hipStream_t stream) {
    const void* feat = d_in[0];
    const void* x    = d_in[1];
    const int* src   = (const int*)d_in[2];
    const int* dst   = (const int*)d_in[3];
    const void* W1   = d_in[4];
    const void* b1   = d_in[5];
    const void* W2   = d_in[6];
    const void* b2   = d_in[7];
    const void* we   = d_in[8];
    const void* be   = d_in[9];
    const void* U1   = d_in[10];
    const void* c1   = d_in[11];
    const void* U2   = d_in[12];
    const void* c2   = d_in[13];
    char* ws = (char*)d_ws;

    if (ws_size >= WS_NEED) {
        float* msum = (float*)(ws + MSUM_OFF);
        int* deg  = (int*)(ws + DEG_OFF);
        int* part = (int*)(ws + PART_OFF);
        int* offs = (int*)(ws + OFFS_OFF);
        int* pos  = (int*)(ws + POS_OFF);
        uint4* epack = (uint4*)(ws + EP_OFF);
        unsigned short* fb  = (unsigned short*)(ws + FB_OFF);
        unsigned short* w1t = (unsigned short*)(ws + W1T_OFF);
        unsigned short* w2t = (unsigned short*)(ws + W2T_OFF);
        unsigned short* u1t = (unsigned short*)(ws + U1T_OFF);
        unsigned short* u2t = (unsigned short*)(ws + U2T_OFF);
        float* cst = (float*)(ws + CST_OFF);

        hipMemsetAsync(ws, 0, ZERO_BYTES, stream);    // msum + deg in one call
        prep_kernel<<<CVT_BLOCKS + PREPW_BLOCKS + HIST_BLOCKS, 256, 0, stream>>>(
            feat, fb, W1, W2, U1, U2, b1, b2, we, be,
            w1t, w2t, u1t, u2t, cst, dst, deg);
        scan1_kernel<<<49, 1024, 0, stream>>>(deg, part);
        scan3_kernel<<<49, 1024, 0, stream>>>(deg, part, offs, pos);
        permute_kernel<<<(N_EDGES + 255) / 256, 256, 0, stream>>>(feat, x, src, dst, pos, epack);
        edge_kernel<true><<<625, 512, 0, stream>>>(fb, w1t, w2t, cst, feat, x, src, dst, epack,
                                                   W1, b1, W2, b2, we, be,
                                                   msum, (unsigned int)(N_NODES * HDIM));
        node_kernel<<<((N_NODES + 15) / 16 + 3) / 4, 256, 0, stream>>>(
            msum, u1t, u2t, feat, U1, c1, U2, c2, d_out);
    } else {
        float* msum = (float*)ws;
        size_t need = (size_t)N_NODES * HDIM * sizeof(float);
        size_t clr  = need < ws_size ? need : ws_size;
        unsigned int cap = (unsigned int)(ws_size / sizeof(float));
        if (cap > (unsigned int)(N_NODES * HDIM)) cap = (unsigned int)(N_NODES * HDIM);

        hipMemsetAsync(msum, 0, clr, stream);
        edge_kernel<false><<<1250, 512, 0, stream>>>(nullptr, nullptr, nullptr, nullptr,
                                                     feat, x, src, dst,
                                                     nullptr, W1, b1, W2, b2, we, be,
                                                     msum, cap);
        node_kernel<<<((N_NODES + 15) / 16 + 3) / 4, 256, 0, stream>>>(
            msum, nullptr, nullptr, feat, U1, c1, U2, c2, d_out);
    }
}